// Round 6
// baseline (745.569 us; speedup 1.0000x reference)
//
#include <hip/hip_runtime.h>
#include <hip/hip_bf16.h>

typedef unsigned short u16;
typedef __attribute__((ext_vector_type(8))) short bf16x8;
typedef __attribute__((ext_vector_type(4))) float f32x4;

// Problem constants: B=8, N=1024, C=768, H=12, D=64, 3C=2304, HID=3072
// rows (both dirs stacked) = 16384; per-dir element count = 8*1024*768 = 6291456
#define DIRSTRIDE 6291456

__device__ __forceinline__ u16 f2bf(float x){
  __hip_bfloat16 h = __float2bfloat16(x);
  return *reinterpret_cast<u16*>(&h);
}
__device__ __forceinline__ float bf2f(u16 u){
  return __uint_as_float(((unsigned int)u) << 16);
}
// cheap bf16 round (half-up): valid for finite non-NaN; P>0 normals here.
__device__ __forceinline__ u16 f2bf_fast(float x){
  return (u16)((__float_as_uint(x) + 0x8000u) >> 16);
}

// XCD-aware block swizzle (T1): nwg%8==0 for all our GEMM grids; bijective.
// Consecutive remapped ids share the A row-panel -> same-XCD L2 reuse.
__device__ __forceinline__ void xcd_remap(int& bx, int& by){
  int gx = (int)gridDim.x;
  int lin = (int)blockIdx.x + gx*(int)blockIdx.y;
  int nwg8 = (gx*(int)gridDim.y) >> 3;
  int rl = (lin & 7)*nwg8 + (lin >> 3);
  bx = rl % gx; by = rl / gx;
}

// ---------------- fallback: zero d_out (diagnostic path if ws too small) -------
__global__ __launch_bounds__(256) void zero_kernel(float* __restrict__ p, int n){
  int i = blockIdx.x*256 + threadIdx.x;
  if (i < n) p[i] = 0.f;
}

// ---------------- fp32 -> bf16 weight conversion ----------------
__global__ __launch_bounds__(256) void cvt_kernel(const float* __restrict__ s,
                                                  u16* __restrict__ d, int n){
  int i = blockIdx.x*256 + threadIdx.x;
  if (i < n) d[i] = f2bf(s[i]);
}

// ---------------- LayerNorm over 768, two stacked sources -> bf16 ----------------
__global__ __launch_bounds__(256) void ln_kernel(const float* __restrict__ s0,
    const float* __restrict__ s1, const float* __restrict__ w,
    const float* __restrict__ b, u16* __restrict__ out,
    float* __restrict__ mu_out, float* __restrict__ rs_out){
  int r = blockIdx.x;
  const float* src = (r < 8192) ? (s0 + (size_t)r*768) : (s1 + (size_t)(r-8192)*768);
  int t = threadIdx.x;
  float v0 = src[t], v1 = src[t+256], v2 = src[t+512];
  __shared__ float red[4];
  float s = v0+v1+v2;
  #pragma unroll
  for (int o=32;o;o>>=1) s += __shfl_xor(s,o);
  if ((t&63)==0) red[t>>6] = s;
  __syncthreads();
  float mean = (red[0]+red[1]+red[2]+red[3]) * (1.0f/768.0f);
  float d0=v0-mean, d1=v1-mean, d2=v2-mean;
  float q = d0*d0+d1*d1+d2*d2;
  __syncthreads();
  #pragma unroll
  for (int o=32;o;o>>=1) q += __shfl_xor(q,o);
  if ((t&63)==0) red[t>>6] = q;
  __syncthreads();
  float var = (red[0]+red[1]+red[2]+red[3]) * (1.0f/768.0f);
  float rstd = rsqrtf(var + 1e-5f);
  if (mu_out && t == 0){ mu_out[r] = mean; rs_out[r] = rstd; }
  size_t base = (size_t)r*768;
  out[base+t]     = f2bf(d0*rstd*w[t]     + b[t]);
  out[base+t+256] = f2bf(d1*rstd*w[t+256] + b[t+256]);
  out[base+t+512] = f2bf(d2*rstd*w[t+512] + b[t+512]);
}

// ---------------- async staging: 128x64 u16 tile, XOR-swizzled ------------------
// T2 swizzle under global_load_lds (rule #21, both-sides-or-neither):
//   LDS dest is LINEAR (wave-uniform base + lane*16, m104 caveat).
//   The 16B chunk within each 128B row is XOR'd with (row&7) on the GLOBAL
//   source address; readers apply the same involution.
__device__ __forceinline__ void stage_tile64(const u16* g, size_t strideK, u16* lds,
                                             int w, int lane){
  #pragma unroll
  for (int i=0;i<4;i++){
    int row = w*32 + i*8 + (lane>>3);
    int cs  = (lane&7) ^ (row&7);            // pre-swizzled source chunk
    const u16* gp = g + (size_t)row*strideK + cs*8;
    __builtin_amdgcn_global_load_lds(
        (const __attribute__((address_space(1))) unsigned int*)gp,
        (__attribute__((address_space(3))) unsigned int*)(lds + (w*4+i)*512),
        16, 0, 0);
  }
}

// 64x64 u16 tile variant (8KB): wave w, instr i covers rows w*16+i*8..+8.
__device__ __forceinline__ void stage_tile64x64(const u16* g, size_t strideK,
                                                u16* lds, int w, int lane){
  #pragma unroll
  for (int i=0;i<2;i++){
    int row = w*16 + i*8 + (lane>>3);
    int cs  = (lane&7) ^ (row&7);            // pre-swizzled source chunk
    const u16* gp = g + (size_t)row*strideK + cs*8;
    __builtin_amdgcn_global_load_lds(
        (const __attribute__((address_space(1))) unsigned int*)gp,
        (__attribute__((address_space(3))) unsigned int*)(lds + (w*2+i)*512),
        16, 0, 0);
  }
}

// Fragment read address for logical (row r, k-chunk c) in a swizzled tile
// (row stride 64 u16): &tile[r*64 + (c ^ (r&7))*8]
#define SWZ_FRAG(tile, r, c) (*(const bf16x8*)&(tile)[(r)*64 + (((c) ^ ((r)&7)))*8])

// ---------------- bf16 MFMA GEMM core (128x128, BK=64, 2-phase dbuf) ------------
// T3 minimum-2-phase: stage(kb+1) issued BEFORE compute(kb); ONE barrier/iter
// (its implicit vmcnt(0)+lgkmcnt(0) drain completes the prefetch AFTER the MFMA
// of tile kb already overlapped the load latency). Race audit: buf[cur^1]'s
// readers finished at the previous barrier; buf[cur]'s data drained there too.
// EPI 2: bf16 out = gelu_exact(dot + bias[col])
// EPI 3: f32 out = dot + bias[col] + resF[flat]   (resF may alias Cout: same idx)
template<int EPI>
__global__ __launch_bounds__(256) void gemm_kernel(
    const u16* __restrict__ A, const u16* __restrict__ W, void* Cout,
    const float* __restrict__ bias, const float* resF,
    int M, int N, int K)
{
  __shared__ __attribute__((aligned(16))) u16 sA[2][128*64];
  __shared__ __attribute__((aligned(16))) u16 sB[2][128*64];
  int t = threadIdx.x;
  int w = t>>6, lane = t&63, ln = lane&15, quad = lane>>4;
  int bx, by; xcd_remap(bx, by);
  int m0 = by*128, n0 = bx*128;
  int wr = (w>>1)*64, wc = (w&1)*64;
  f32x4 acc[4][4];
  #pragma unroll
  for (int mi=0;mi<4;mi++)
    #pragma unroll
    for (int ni=0;ni<4;ni++) acc[mi][ni] = (f32x4){0.f,0.f,0.f,0.f};
  int KB = K >> 6;
  stage_tile64(A + (size_t)m0*K, K, sA[0], w, lane);
  stage_tile64(W + (size_t)n0*K, K, sB[0], w, lane);
  __syncthreads();
  int cur = 0;
  for (int kb=0;kb<KB;kb++){
    if (kb+1 < KB){
      stage_tile64(A + (size_t)m0*K + (kb+1)*64, K, sA[cur^1], w, lane);
      stage_tile64(W + (size_t)n0*K + (kb+1)*64, K, sB[cur^1], w, lane);
    }
    const u16* pA = sA[cur];
    const u16* pB = sB[cur];
    #pragma unroll
    for (int ks=0;ks<2;ks++){
      bf16x8 aF[4], bF[4];
      #pragma unroll
      for (int mi=0;mi<4;mi++) aF[mi] = SWZ_FRAG(pA, wr+mi*16+ln, ks*4+quad);
      #pragma unroll
      for (int ni=0;ni<4;ni++) bF[ni] = SWZ_FRAG(pB, wc+ni*16+ln, ks*4+quad);
      #pragma unroll
      for (int mi=0;mi<4;mi++)
        #pragma unroll
        for (int ni=0;ni<4;ni++)
          acc[mi][ni] = __builtin_amdgcn_mfma_f32_16x16x32_bf16(aF[mi], bF[ni], acc[mi][ni], 0,0,0);
    }
    __syncthreads();          // prefetch drained + all reads of buf[cur] done
    cur ^= 1;
  }
  #pragma unroll
  for (int mi=0;mi<4;mi++){
    #pragma unroll
    for (int ni=0;ni<4;ni++){
      #pragma unroll
      for (int r=0;r<4;r++){
        int row = m0 + wr + mi*16 + quad*4 + r;
        int col = n0 + wc + ni*16 + ln;
        size_t ridx = (size_t)row*N + col;
        float v = acc[mi][ni][r];
        if (EPI == 2){
          v += bias[col];
          v = 0.5f*v*(1.0f + erff(v*0.70710678118654752f));
          ((u16*)Cout)[ridx] = f2bf(v);
        } else {
          float rf = resF[ridx];          // may be same address as Cout[ridx]
          ((float*)Cout)[ridx] = v + bias[col] + rf;
        }
      }
    }
  }
}

// ---------------- proj GEMM with fused residuals (2-phase dbuf core) ------------
// h1 = ctx @ proj_w^T + proj_b + q_scrambled(opposite stream) + recomputed LN(x).
__global__ __launch_bounds__(256) void gemm_proj_kernel(
    const u16* __restrict__ A, const u16* __restrict__ W, float* Cout,
    const float* __restrict__ bias, const u16* __restrict__ resQ,
    const float* __restrict__ before, const float* __restrict__ after,
    const float* __restrict__ n1w, const float* __restrict__ n1b,
    const float* __restrict__ mu, const float* __restrict__ rstd)
{
  const int K = 768, N = 768, KB = 12;
  __shared__ __attribute__((aligned(16))) u16 sA[2][128*64];
  __shared__ __attribute__((aligned(16))) u16 sB[2][128*64];
  int t = threadIdx.x;
  int w = t>>6, lane = t&63, ln = lane&15, quad = lane>>4;
  int bx, by; xcd_remap(bx, by);
  int m0 = by*128, n0 = bx*128;
  int wr = (w>>1)*64, wc = (w&1)*64;
  f32x4 acc[4][4];
  #pragma unroll
  for (int mi=0;mi<4;mi++)
    #pragma unroll
    for (int ni=0;ni<4;ni++) acc[mi][ni] = (f32x4){0.f,0.f,0.f,0.f};
  stage_tile64(A + (size_t)m0*K, K, sA[0], w, lane);
  stage_tile64(W + (size_t)n0*K, K, sB[0], w, lane);
  __syncthreads();
  int cur = 0;
  for (int kb=0;kb<KB;kb++){
    if (kb+1 < KB){
      stage_tile64(A + (size_t)m0*K + (kb+1)*64, K, sA[cur^1], w, lane);
      stage_tile64(W + (size_t)n0*K + (kb+1)*64, K, sB[cur^1], w, lane);
    }
    const u16* pA = sA[cur];
    const u16* pB = sB[cur];
    #pragma unroll
    for (int ks=0;ks<2;ks++){
      bf16x8 aF[4], bF[4];
      #pragma unroll
      for (int mi=0;mi<4;mi++) aF[mi] = SWZ_FRAG(pA, wr+mi*16+ln, ks*4+quad);
      #pragma unroll
      for (int ni=0;ni<4;ni++) bF[ni] = SWZ_FRAG(pB, wc+ni*16+ln, ks*4+quad);
      #pragma unroll
      for (int mi=0;mi<4;mi++)
        #pragma unroll
        for (int ni=0;ni<4;ni++)
          acc[mi][ni] = __builtin_amdgcn_mfma_f32_16x16x32_bf16(aF[mi], bF[ni], acc[mi][ni], 0,0,0);
    }
    __syncthreads();
    cur ^= 1;
  }
  #pragma unroll
  for (int mi=0;mi<4;mi++){
    #pragma unroll
    for (int ni=0;ni<4;ni++){
      #pragma unroll
      for (int r=0;r<4;r++){
        int row = m0 + wr + mi*16 + quad*4 + r;
        int col = n0 + wc + ni*16 + ln;
        size_t ridx = (size_t)row*N + col;
        int dirout = row >> 13;
        int rem = row & 8191;
        // faithful q.reshape(B,N,H*D): flat per-batch add of (H,N,D) buffer;
        // q comes from the OPPOSITE stream (context_b uses q_a and vice versa)
        size_t qidx = (size_t)(1-dirout)*DIRSTRIDE + (size_t)rem*768 + col;
        const float* src = dirout ? after : before;
        float xr = (src[(size_t)rem*768 + col] - mu[row]) * rstd[row] * n1w[col] + n1b[col];
        Cout[ridx] = acc[mi][ni][r] + bias[col] + bf2f(resQ[qidx]) + xr;
      }
    }
  }
}

// ---------------- qkv GEMM, per-head LN epilogue (2-phase dbuf core) ------------
__global__ __launch_bounds__(256) void gemm_qkv_kernel(
    const u16* __restrict__ A, const u16* __restrict__ W,
    const float* __restrict__ hw, const float* __restrict__ hb,
    u16* __restrict__ q, u16* __restrict__ k, u16* __restrict__ vt)
{
  const int K = 768, KB = 12;
  __shared__ __attribute__((aligned(16))) u16 sA[2][128*64];
  __shared__ __attribute__((aligned(16))) u16 sB[2][128*64];
  int t = threadIdx.x;
  int w = t>>6, lane = t&63, ln = lane&15, quad = lane>>4;
  int bx, by; xcd_remap(bx, by);
  int m0 = by*128, n0 = bx*128;
  int wr = (w>>1)*64, wc = (w&1)*64;
  f32x4 acc[4][4];
  #pragma unroll
  for (int mi=0;mi<4;mi++)
    #pragma unroll
    for (int ni=0;ni<4;ni++) acc[mi][ni] = (f32x4){0.f,0.f,0.f,0.f};
  stage_tile64(A + (size_t)m0*K, K, sA[0], w, lane);
  stage_tile64(W + (size_t)n0*K, K, sB[0], w, lane);
  __syncthreads();
  int cur = 0;
  for (int kb=0;kb<KB;kb++){
    if (kb+1 < KB){
      stage_tile64(A + (size_t)m0*K + (kb+1)*64, K, sA[cur^1], w, lane);
      stage_tile64(W + (size_t)n0*K + (kb+1)*64, K, sB[cur^1], w, lane);
    }
    const u16* pA = sA[cur];
    const u16* pB = sB[cur];
    #pragma unroll
    for (int ks=0;ks<2;ks++){
      bf16x8 aF[4], bF[4];
      #pragma unroll
      for (int mi=0;mi<4;mi++) aF[mi] = SWZ_FRAG(pA, wr+mi*16+ln, ks*4+quad);
      #pragma unroll
      for (int ni=0;ni<4;ni++) bF[ni] = SWZ_FRAG(pB, wc+ni*16+ln, ks*4+quad);
      #pragma unroll
      for (int mi=0;mi<4;mi++)
        #pragma unroll
        for (int ni=0;ni<4;ni++)
          acc[mi][ni] = __builtin_amdgcn_mfma_f32_16x16x32_bf16(aF[mi], bF[ni], acc[mi][ni], 0,0,0);
    }
    __syncthreads();
    cur ^= 1;
  }
  // epilogue: per-row (64-wide) LayerNorm, then scatter
  int sec = (n0 + wc) >> 6;          // 0..35, wave-uniform
  int which = sec / 12, h = sec - which*12;
  float hwv[4], hbv[4];
  #pragma unroll
  for (int ni=0;ni<4;ni++){ hwv[ni] = hw[ni*16+ln]; hbv[ni] = hb[ni*16+ln]; }
  #pragma unroll
  for (int mi=0;mi<4;mi++){
    #pragma unroll
    for (int r=0;r<4;r++){
      float s = acc[mi][0][r]+acc[mi][1][r]+acc[mi][2][r]+acc[mi][3][r];
      #pragma unroll
      for (int ofs=1; ofs<16; ofs<<=1) s += __shfl_xor(s, ofs);
      float mu = s * (1.0f/64.0f);
      float vv = 0.f;
      #pragma unroll
      for (int ni=0;ni<4;ni++){ float d = acc[mi][ni][r]-mu; vv += d*d; }
      #pragma unroll
      for (int ofs=1; ofs<16; ofs<<=1) vv += __shfl_xor(vv, ofs);
      float rstd = rsqrtf(vv*(1.0f/64.0f) + 1e-5f);
      int token = m0 + wr + mi*16 + quad*4 + r;
      int dir = token >> 13, bb = (token>>10)&7, n = token & 1023;
      size_t base = (size_t)dir*DIRSTRIDE + (size_t)bb*786432 + (size_t)h*65536;
      #pragma unroll
      for (int ni=0;ni<4;ni++){
        u16 y = f2bf((acc[mi][ni][r]-mu)*rstd*hwv[ni] + hbv[ni]);
        int hd = ni*16 + ln;
        if (which == 0)      q[base + (size_t)n*64 + hd] = y;
        else if (which == 1) k[base + (size_t)n*64 + hd] = y;
        else                 vt[base + (size_t)hd*1024 + n] = y;
      }
    }
  }
}

// ---------------- flash attention v7: async staging, dbuf, softmax diet --------
// (unchanged from r5: 134us, VALU-bound; GEMM pool is the bigger lever)
__global__ __launch_bounds__(256) void flash_kernel(const u16* __restrict__ qg,
    const u16* __restrict__ kg, const u16* __restrict__ vtg, u16* __restrict__ ctx)
{
  __shared__ __attribute__((aligned(16))) u16 sK[2][64*64];
  __shared__ __attribute__((aligned(16))) u16 sV[2][64*64];
  __shared__ __attribute__((aligned(16))) u16 sP[4*16*72];
  // XCD co-location: all 16 qt-blocks of one (b,h,dout) on the same XCD.
  int lin = (int)blockIdx.x + 16*((int)blockIdx.y + 96*(int)blockIdx.z);
  int x8 = lin & 7, jj = lin >> 3;
  int qt = jj & 15;
  int g  = x8 + 8*(jj >> 4);            // 0..191, bijective
  int dout = g & 1, bh = g >> 1;
  int b = bh/12, h = bh - b*12;
  size_t qbase = (size_t)(1-dout)*DIRSTRIDE + (size_t)b*786432 + (size_t)h*65536;
  size_t kbase = (size_t)dout*DIRSTRIDE + (size_t)b*786432 + (size_t)h*65536;
  int t = threadIdx.x;
  int w = t>>6, lane = t&63, ln = lane&15, quad = lane>>4;
  // Q fragment in registers for the whole loop: A[m=ln][k=quad*8+j (+32)]
  const u16* qp = qg + qbase + (size_t)(qt*64 + w*16 + ln)*64 + quad*8;
  bf16x8 aQ0 = *(const bf16x8*)qp;
  bf16x8 aQ1 = *(const bf16x8*)(qp + 32);
  bf16x8 vOne;
  #pragma unroll
  for (int j=0;j<8;j++) vOne[j] = (short)0x3F80;   // bf16 1.0
  f32x4 o[4];
  #pragma unroll
  for (int ni=0;ni<4;ni++) o[ni] = (f32x4){0.f,0.f,0.f,0.f};
  f32x4 oL = (f32x4){0.f,0.f,0.f,0.f};             // row-sums of P (softmax denom)
  u16* pw = &sP[w*16*72];
  const float cs = 0.18033688011112042f;   // 0.125 * log2(e)
  // prologue: stage tile kt=0 into buffer 0
  stage_tile64x64(kg  + kbase, 64, sK[0], w, lane);               // K rows: [kt*64+n][d]
  stage_tile64x64(vtg + kbase, 1024, sV[0], w, lane);             // V^T rows: [d][kt*64+n]
  __syncthreads();
  int cur = 0;
  for (int kt=0;kt<16;kt++){
    // stage next tile into the other buffer (async; drains at end-of-iter barrier)
    if (kt < 15){
      stage_tile64x64(kg  + kbase + (size_t)(kt+1)*4096, 64, sK[cur^1], w, lane);
      stage_tile64x64(vtg + kbase + (size_t)(kt+1)*64, 1024, sV[cur^1], w, lane);
    }
    const u16* sKc = sK[cur];
    const u16* sVc = sV[cur];
    // K fragments: B[n=kv=ni*16+ln][k=d=quad*8+j(+32)]
    bf16x8 bK[4][2], bV[4][2];
    #pragma unroll
    for (int ni=0;ni<4;ni++){
      int rr = ni*16 + ln;
      bK[ni][0] = SWZ_FRAG(sKc, rr, quad);
      bK[ni][1] = SWZ_FRAG(sKc, rr, 4+quad);
      // V fragments: B[n=d=ni*16+ln][k=kv-local=quad*8+j(+32)]
      bV[ni][0] = SWZ_FRAG(sVc, rr, quad);
      bV[ni][1] = SWZ_FRAG(sVc, rr, 4+quad);
    }
    f32x4 s[4];
    __builtin_amdgcn_s_setprio(1);
    #pragma unroll
    for (int ni=0;ni<4;ni++){
      s[ni] = (f32x4){0.f,0.f,0.f,0.f};
      s[ni] = __builtin_amdgcn_mfma_f32_16x16x32_bf16(aQ0, bK[ni][0], s[ni], 0,0,0);
      s[ni] = __builtin_amdgcn_mfma_f32_16x16x32_bf16(aQ1, bK[ni][1], s[ni], 0,0,0);
    }
    __builtin_amdgcn_s_setprio(0);
    // p = exp2(cs*s); bounded, no clamp; cheap half-up bf16 round
    #pragma unroll
    for (int ni=0;ni<4;ni++){
      #pragma unroll
      for (int r=0;r<4;r++){
        float p = exp2f(s[ni][r]*cs);
        pw[(quad*4+r)*72 + ni*16 + ln] = f2bf_fast(p);
      }
    }
    // NO barrier: pw is wave-private; compiler orders ds write->read via lgkmcnt
    bf16x8 aP0 = *(const bf16x8*)&pw[ln*72 + quad*8];
    bf16x8 aP1 = *(const bf16x8*)&pw[ln*72 + 32 + quad*8];
    __builtin_amdgcn_s_setprio(1);
    #pragma unroll
    for (int ni=0;ni<4;ni++){
      o[ni] = __builtin_amdgcn_mfma_f32_16x16x32_bf16(aP0, bV[ni][0], o[ni], 0,0,0);
      o[ni] = __builtin_amdgcn_mfma_f32_16x16x32_bf16(aP1, bV[ni][1], o[ni], 0,0,0);
    }
    oL = __builtin_amdgcn_mfma_f32_16x16x32_bf16(aP0, vOne, oL, 0,0,0);
    oL = __builtin_amdgcn_mfma_f32_16x16x32_bf16(aP1, vOne, oL, 0,0,0);
    __builtin_amdgcn_s_setprio(0);
    __syncthreads();          // single barrier/iter: next tile staged + readable
    cur ^= 1;
  }
  #pragma unroll
  for (int ni=0;ni<4;ni++){
    #pragma unroll
    for (int r=0;r<4;r++){
      int row = qt*64 + w*16 + quad*4 + r;
      float val = o[ni][r] / oL[r];
      ctx[((size_t)dout*8192 + (size_t)b*1024 + row)*768 + h*64 + ni*16 + ln] = f2bf(val);
    }
  }
}

// ---------------- launcher ----------------
// Workspace layout (bytes) — total 114,950,144 (~110 MiB); h1 f32 lives in d_out.
//   [0,          25165824)  xn bf16    (ln -> qkv gemm), then ctx bf16 (flash -> proj)
//   [25165824,   50331648)  q bf16     (qkv -> proj)
//       [0, 50331648)       g bf16 chunk scratch for MLP (after proj)
//   [50331648,   75497472)  k bf16     (qkv -> flash), then h1n bf16 (ln2 -> fc1)
//   [75497472,  100663296)  vt bf16    (qkv -> flash)
//   [100663296, 114819072)  bf16 weights (qkv,proj,fc1,fc2)
//   [114819072, 114950144)  norm1 mu/rstd f32[16384] each
extern "C" void kernel_launch(void* const* d_in, const int* in_sizes, int n_in,
                              void* d_out, int out_size, void* d_ws, size_t ws_size,
                              hipStream_t stream)
{
  const float* before = (const float*)d_in[0];
  const float* after  = (const float*)d_in[1];
  const float* n1w  = (const float*)d_in[2];
  const float* n1b  = (const float*)d_in[3];
  const float* qkvw = (const float*)d_in[4];
  const float* hlnw = (const float*)d_in[5];
  const float* hlnb = (const float*)d_in[6];
  const float* projw= (const float*)d_in[7];
  const float* projb= (const float*)d_in[8];
  const float* n2w  = (const float*)d_in[9];
  const float* n2b  = (const float*)d_in[10];
  const float* fc1w = (const float*)d_in[11];
  const float* fc1b = (const float*)d_in[12];
  const float* fc2w = (const float*)d_in[13];
  const float* fc2b = (const float*)d_in[14];

  const size_t REQUIRED = 114950144;
  if (ws_size < REQUIRED){
    // Diagnostic fallback: never touch d_ws; clean test failure instead of fault.
    zero_kernel<<<(out_size + 255)/256, 256, 0, stream>>>((float*)d_out, out_size);
    return;
  }

  char* ws = (char*)d_ws;
  u16* xn    = (u16*)(ws + 0);
  u16* ctxb  = (u16*)(ws + 0);            // reuse xn slot (xn dead after qkv gemm)
  u16* gbuf  = (u16*)(ws + 0);            // MLP chunk scratch (ctx+q dead by then)
  u16* qb    = (u16*)(ws + 25165824);
  u16* kb    = (u16*)(ws + 50331648);
  u16* h1n   = (u16*)(ws + 50331648);     // reuse k slot (k dead after flash)
  u16* vtb   = (u16*)(ws + 75497472);
  u16* wqkv  = (u16*)(ws + 100663296);
  u16* wproj = (u16*)(ws + 104202240);
  u16* wfc1  = (u16*)(ws + 105381888);
  u16* wfc2  = (u16*)(ws + 110100480);
  float* mu1  = (float*)(ws + 114819072);
  float* rs1  = (float*)(ws + 114884608);
  float* h1   = (float*)d_out;            // h1 f32 scratch lives in d_out
  float* outp = (float*)d_out;

  cvt_kernel<<<6912, 256, 0, stream>>>(qkvw, wqkv, 1769472);
  cvt_kernel<<<2304, 256, 0, stream>>>(projw, wproj, 589824);
  cvt_kernel<<<9216, 256, 0, stream>>>(fc1w, wfc1, 2359296);
  cvt_kernel<<<9216, 256, 0, stream>>>(fc2w, wfc2, 2359296);

  // 1) LN(before), LN(after) -> xn bf16 (+ stats for residual recompute)
  ln_kernel<<<16384, 256, 0, stream>>>(before, after, n1w, n1b, xn, mu1, rs1);
  // 2) qkv = xn @ qkv_w^T, fused per-head LN, scatter to q,k,v^T (xn dies here)
  gemm_qkv_kernel<<<dim3(18,128), 256, 0, stream>>>(xn, wqkv, hlnw, hlnb, qb, kb, vtb);
  // 3) cross attention; ctx overwrites xn slot (dirout0: q from after, k/v from before)
  flash_kernel<<<dim3(16,96,2), 256, 0, stream>>>(qb, kb, vtb, ctxb);
  // 4) h1 = ctx @ proj_w^T + proj_b + q_scrambled + LN(x) recomputed  (f32, into d_out)
  gemm_proj_kernel<<<dim3(6,128), 256, 0, stream>>>(ctxb, wproj, h1,
      projb, qb, before, after, n1w, n1b, mu1, rs1);
  // 5) h1n = LN(h1) bf16 (k slot)
  ln_kernel<<<16384, 256, 0, stream>>>(h1, h1 + (size_t)8192*768, n2w, n2b, h1n,
      nullptr, nullptr);
  // 6/7) MLP in two row-chunks of 8192 (g scratch = 50.3 MB in ctx+q slots)
  for (int c = 0; c < 2; c++){
    size_t off = (size_t)c * 8192 * 768;       // elements into (16384,768)
    gemm_kernel<2><<<dim3(24,64), 256, 0, stream>>>(h1n + off, wfc1, gbuf,
        fc1b, nullptr, 8192, 3072, 768);
    gemm_kernel<3><<<dim3(6,64), 256, 0, stream>>>(gbuf, wfc2, outp + off,
        fc2b, h1 + off, 8192, 768, 3072);
  }
}

// Round 7
// 721.056 us; speedup vs baseline: 1.0340x; 1.0340x over previous
//
#include <hip/hip_runtime.h>
#include <hip/hip_bf16.h>

typedef unsigned short u16;
typedef __attribute__((ext_vector_type(8))) short bf16x8;
typedef __attribute__((ext_vector_type(4))) float f32x4;

// Problem constants: B=8, N=1024, C=768, H=12, D=64, 3C=2304, HID=3072
// rows (both dirs stacked) = 16384; per-dir element count = 8*1024*768 = 6291456
#define DIRSTRIDE 6291456

__device__ __forceinline__ u16 f2bf(float x){
  __hip_bfloat16 h = __float2bfloat16(x);
  return *reinterpret_cast<u16*>(&h);
}
__device__ __forceinline__ float bf2f(u16 u){
  return __uint_as_float(((unsigned int)u) << 16);
}
// cheap bf16 round (half-up): valid for finite non-NaN; P>0 normals here.
__device__ __forceinline__ u16 f2bf_fast(float x){
  return (u16)((__float_as_uint(x) + 0x8000u) >> 16);
}

// XCD-aware block swizzle (T1): nwg%8==0 for all our GEMM grids; bijective.
// Consecutive remapped ids share the A row-panel -> same-XCD L2 reuse.
__device__ __forceinline__ void xcd_remap(int& bx, int& by){
  int gx = (int)gridDim.x;
  int lin = (int)blockIdx.x + gx*(int)blockIdx.y;
  int nwg8 = (gx*(int)gridDim.y) >> 3;
  int rl = (lin & 7)*nwg8 + (lin >> 3);
  bx = rl % gx; by = rl / gx;
}

// ---------------- fallback: zero d_out (diagnostic path if ws too small) -------
__global__ __launch_bounds__(256) void zero_kernel(float* __restrict__ p, int n){
  int i = blockIdx.x*256 + threadIdx.x;
  if (i < n) p[i] = 0.f;
}

// ---------------- fp32 -> bf16 weight conversion ----------------
__global__ __launch_bounds__(256) void cvt_kernel(const float* __restrict__ s,
                                                  u16* __restrict__ d, int n){
  int i = blockIdx.x*256 + threadIdx.x;
  if (i < n) d[i] = f2bf(s[i]);
}

// ---------------- LayerNorm over 768, two stacked sources -> bf16 ----------------
__global__ __launch_bounds__(256) void ln_kernel(const float* __restrict__ s0,
    const float* __restrict__ s1, const float* __restrict__ w,
    const float* __restrict__ b, u16* __restrict__ out,
    float* __restrict__ mu_out, float* __restrict__ rs_out){
  int r = blockIdx.x;
  const float* src = (r < 8192) ? (s0 + (size_t)r*768) : (s1 + (size_t)(r-8192)*768);
  int t = threadIdx.x;
  float v0 = src[t], v1 = src[t+256], v2 = src[t+512];
  __shared__ float red[4];
  float s = v0+v1+v2;
  #pragma unroll
  for (int o=32;o;o>>=1) s += __shfl_xor(s,o);
  if ((t&63)==0) red[t>>6] = s;
  __syncthreads();
  float mean = (red[0]+red[1]+red[2]+red[3]) * (1.0f/768.0f);
  float d0=v0-mean, d1=v1-mean, d2=v2-mean;
  float q = d0*d0+d1*d1+d2*d2;
  __syncthreads();
  #pragma unroll
  for (int o=32;o;o>>=1) q += __shfl_xor(q,o);
  if ((t&63)==0) red[t>>6] = q;
  __syncthreads();
  float var = (red[0]+red[1]+red[2]+red[3]) * (1.0f/768.0f);
  float rstd = rsqrtf(var + 1e-5f);
  if (mu_out && t == 0){ mu_out[r] = mean; rs_out[r] = rstd; }
  size_t base = (size_t)r*768;
  out[base+t]     = f2bf(d0*rstd*w[t]     + b[t]);
  out[base+t+256] = f2bf(d1*rstd*w[t+256] + b[t+256]);
  out[base+t+512] = f2bf(d2*rstd*w[t+512] + b[t+512]);
}

// ---------------- async staging: 128x64 u16 tile, XOR-swizzled ------------------
// T2 swizzle under global_load_lds (rule #21, both-sides-or-neither):
//   LDS dest is LINEAR (wave-uniform base + lane*16, m104 caveat).
//   The 16B chunk within each 128B row is XOR'd with (row&7) on the GLOBAL
//   source address; readers apply the same involution.
__device__ __forceinline__ void stage_tile64(const u16* g, size_t strideK, u16* lds,
                                             int w, int lane){
  #pragma unroll
  for (int i=0;i<4;i++){
    int row = w*32 + i*8 + (lane>>3);
    int cs  = (lane&7) ^ (row&7);            // pre-swizzled source chunk
    const u16* gp = g + (size_t)row*strideK + cs*8;
    __builtin_amdgcn_global_load_lds(
        (const __attribute__((address_space(1))) unsigned int*)gp,
        (__attribute__((address_space(3))) unsigned int*)(lds + (w*4+i)*512),
        16, 0, 0);
  }
}

// 64x64 u16 tile variant (8KB): wave w, instr i covers rows w*16+i*8..+8.
__device__ __forceinline__ void stage_tile64x64(const u16* g, size_t strideK,
                                                u16* lds, int w, int lane){
  #pragma unroll
  for (int i=0;i<2;i++){
    int row = w*16 + i*8 + (lane>>3);
    int cs  = (lane&7) ^ (row&7);            // pre-swizzled source chunk
    const u16* gp = g + (size_t)row*strideK + cs*8;
    __builtin_amdgcn_global_load_lds(
        (const __attribute__((address_space(1))) unsigned int*)gp,
        (__attribute__((address_space(3))) unsigned int*)(lds + (w*2+i)*512),
        16, 0, 0);
  }
}

// Fragment read address for logical (row r, k-chunk c) in a swizzled tile
// (row stride 64 u16): &tile[r*64 + (c ^ (r&7))*8]
#define SWZ_FRAG(tile, r, c) (*(const bf16x8*)&(tile)[(r)*64 + (((c) ^ ((r)&7)))*8])

// ---- counted-vmcnt dbuf K-loop (T3+T4): never drain vmcnt(0) in the loop ------
// Each wave: 8 global_load_lds in flight for tile kb+1 while computing kb.
// wait vmcnt(8) -> MY kb loads landed; s_barrier -> ALL waves' kb loads landed
// (each wave waited its own before arriving). Second barrier protects buf[cur]
// from iter-kb+2's DMA overwrite. sched_barrier(0) pins ds_read/stage motion
// across the raw barriers (rule #18 hazard).

// ---------------- bf16 MFMA GEMM core (128x128, BK=64, counted-vmcnt dbuf) ------
// EPI 2: bf16 out = gelu_exact(dot + bias[col])
// EPI 3: f32 out = dot + bias[col] + resF[flat]   (resF may alias Cout: same idx)
template<int EPI>
__global__ __launch_bounds__(256) void gemm_kernel(
    const u16* __restrict__ A, const u16* __restrict__ W, void* Cout,
    const float* __restrict__ bias, const float* resF,
    int M, int N, int K)
{
  __shared__ __attribute__((aligned(16))) u16 sA[2][128*64];
  __shared__ __attribute__((aligned(16))) u16 sB[2][128*64];
  int t = threadIdx.x;
  int w = t>>6, lane = t&63, ln = lane&15, quad = lane>>4;
  int bx, by; xcd_remap(bx, by);
  int m0 = by*128, n0 = bx*128;
  int wr = (w>>1)*64, wc = (w&1)*64;
  f32x4 acc[4][4];
  #pragma unroll
  for (int mi=0;mi<4;mi++)
    #pragma unroll
    for (int ni=0;ni<4;ni++) acc[mi][ni] = (f32x4){0.f,0.f,0.f,0.f};
  int KB = K >> 6;
  stage_tile64(A + (size_t)m0*K, K, sA[0], w, lane);
  stage_tile64(W + (size_t)n0*K, K, sB[0], w, lane);
  int cur = 0;
  for (int kb=0;kb<KB;kb++){
    if (kb+1 < KB){
      stage_tile64(A + (size_t)m0*K + (kb+1)*64, K, sA[cur^1], w, lane);
      stage_tile64(W + (size_t)n0*K + (kb+1)*64, K, sB[cur^1], w, lane);
      asm volatile("s_waitcnt vmcnt(8)" ::: "memory");
    } else {
      asm volatile("s_waitcnt vmcnt(0)" ::: "memory");
    }
    __builtin_amdgcn_s_barrier();
    __builtin_amdgcn_sched_barrier(0);
    const u16* pA = sA[cur];
    const u16* pB = sB[cur];
    #pragma unroll
    for (int ks=0;ks<2;ks++){
      bf16x8 aF[4], bF[4];
      #pragma unroll
      for (int mi=0;mi<4;mi++) aF[mi] = SWZ_FRAG(pA, wr+mi*16+ln, ks*4+quad);
      #pragma unroll
      for (int ni=0;ni<4;ni++) bF[ni] = SWZ_FRAG(pB, wc+ni*16+ln, ks*4+quad);
      #pragma unroll
      for (int mi=0;mi<4;mi++)
        #pragma unroll
        for (int ni=0;ni<4;ni++)
          acc[mi][ni] = __builtin_amdgcn_mfma_f32_16x16x32_bf16(aF[mi], bF[ni], acc[mi][ni], 0,0,0);
    }
    __builtin_amdgcn_sched_barrier(0);
    __builtin_amdgcn_s_barrier();          // all reads of buf[cur] done
    __builtin_amdgcn_sched_barrier(0);
    cur ^= 1;
  }
  #pragma unroll
  for (int mi=0;mi<4;mi++){
    #pragma unroll
    for (int ni=0;ni<4;ni++){
      #pragma unroll
      for (int r=0;r<4;r++){
        int row = m0 + wr + mi*16 + quad*4 + r;
        int col = n0 + wc + ni*16 + ln;
        size_t ridx = (size_t)row*N + col;
        float v = acc[mi][ni][r];
        if (EPI == 2){
          v += bias[col];
          v = 0.5f*v*(1.0f + erff(v*0.70710678118654752f));
          ((u16*)Cout)[ridx] = f2bf(v);
        } else {
          float rf = resF[ridx];          // may be same address as Cout[ridx]
          ((float*)Cout)[ridx] = v + bias[col] + rf;
        }
      }
    }
  }
}

// ---------------- proj GEMM with fused residuals (counted-vmcnt dbuf core) ------
// h1 = ctx @ proj_w^T + proj_b + q_scrambled(opposite stream) + recomputed LN(x).
__global__ __launch_bounds__(256) void gemm_proj_kernel(
    const u16* __restrict__ A, const u16* __restrict__ W, float* Cout,
    const float* __restrict__ bias, const u16* __restrict__ resQ,
    const float* __restrict__ before, const float* __restrict__ after,
    const float* __restrict__ n1w, const float* __restrict__ n1b,
    const float* __restrict__ mu, const float* __restrict__ rstd)
{
  const int K = 768, N = 768, KB = 12;
  __shared__ __attribute__((aligned(16))) u16 sA[2][128*64];
  __shared__ __attribute__((aligned(16))) u16 sB[2][128*64];
  int t = threadIdx.x;
  int w = t>>6, lane = t&63, ln = lane&15, quad = lane>>4;
  int bx, by; xcd_remap(bx, by);
  int m0 = by*128, n0 = bx*128;
  int wr = (w>>1)*64, wc = (w&1)*64;
  f32x4 acc[4][4];
  #pragma unroll
  for (int mi=0;mi<4;mi++)
    #pragma unroll
    for (int ni=0;ni<4;ni++) acc[mi][ni] = (f32x4){0.f,0.f,0.f,0.f};
  stage_tile64(A + (size_t)m0*K, K, sA[0], w, lane);
  stage_tile64(W + (size_t)n0*K, K, sB[0], w, lane);
  int cur = 0;
  for (int kb=0;kb<KB;kb++){
    if (kb+1 < KB){
      stage_tile64(A + (size_t)m0*K + (kb+1)*64, K, sA[cur^1], w, lane);
      stage_tile64(W + (size_t)n0*K + (kb+1)*64, K, sB[cur^1], w, lane);
      asm volatile("s_waitcnt vmcnt(8)" ::: "memory");
    } else {
      asm volatile("s_waitcnt vmcnt(0)" ::: "memory");
    }
    __builtin_amdgcn_s_barrier();
    __builtin_amdgcn_sched_barrier(0);
    const u16* pA = sA[cur];
    const u16* pB = sB[cur];
    #pragma unroll
    for (int ks=0;ks<2;ks++){
      bf16x8 aF[4], bF[4];
      #pragma unroll
      for (int mi=0;mi<4;mi++) aF[mi] = SWZ_FRAG(pA, wr+mi*16+ln, ks*4+quad);
      #pragma unroll
      for (int ni=0;ni<4;ni++) bF[ni] = SWZ_FRAG(pB, wc+ni*16+ln, ks*4+quad);
      #pragma unroll
      for (int mi=0;mi<4;mi++)
        #pragma unroll
        for (int ni=0;ni<4;ni++)
          acc[mi][ni] = __builtin_amdgcn_mfma_f32_16x16x32_bf16(aF[mi], bF[ni], acc[mi][ni], 0,0,0);
    }
    __builtin_amdgcn_sched_barrier(0);
    __builtin_amdgcn_s_barrier();
    __builtin_amdgcn_sched_barrier(0);
    cur ^= 1;
  }
  #pragma unroll
  for (int mi=0;mi<4;mi++){
    #pragma unroll
    for (int ni=0;ni<4;ni++){
      #pragma unroll
      for (int r=0;r<4;r++){
        int row = m0 + wr + mi*16 + quad*4 + r;
        int col = n0 + wc + ni*16 + ln;
        size_t ridx = (size_t)row*N + col;
        int dirout = row >> 13;
        int rem = row & 8191;
        // faithful q.reshape(B,N,H*D): flat per-batch add of (H,N,D) buffer;
        // q comes from the OPPOSITE stream (context_b uses q_a and vice versa)
        size_t qidx = (size_t)(1-dirout)*DIRSTRIDE + (size_t)rem*768 + col;
        const float* src = dirout ? after : before;
        float xr = (src[(size_t)rem*768 + col] - mu[row]) * rstd[row] * n1w[col] + n1b[col];
        Cout[ridx] = acc[mi][ni][r] + bias[col] + bf2f(resQ[qidx]) + xr;
      }
    }
  }
}

// ---------------- qkv GEMM, per-head LN epilogue (counted-vmcnt dbuf core) ------
__global__ __launch_bounds__(256) void gemm_qkv_kernel(
    const u16* __restrict__ A, const u16* __restrict__ W,
    const float* __restrict__ hw, const float* __restrict__ hb,
    u16* __restrict__ q, u16* __restrict__ k, u16* __restrict__ vt)
{
  const int K = 768, KB = 12;
  __shared__ __attribute__((aligned(16))) u16 sA[2][128*64];
  __shared__ __attribute__((aligned(16))) u16 sB[2][128*64];
  int t = threadIdx.x;
  int w = t>>6, lane = t&63, ln = lane&15, quad = lane>>4;
  int bx, by; xcd_remap(bx, by);
  int m0 = by*128, n0 = bx*128;
  int wr = (w>>1)*64, wc = (w&1)*64;
  f32x4 acc[4][4];
  #pragma unroll
  for (int mi=0;mi<4;mi++)
    #pragma unroll
    for (int ni=0;ni<4;ni++) acc[mi][ni] = (f32x4){0.f,0.f,0.f,0.f};
  stage_tile64(A + (size_t)m0*K, K, sA[0], w, lane);
  stage_tile64(W + (size_t)n0*K, K, sB[0], w, lane);
  int cur = 0;
  for (int kb=0;kb<KB;kb++){
    if (kb+1 < KB){
      stage_tile64(A + (size_t)m0*K + (kb+1)*64, K, sA[cur^1], w, lane);
      stage_tile64(W + (size_t)n0*K + (kb+1)*64, K, sB[cur^1], w, lane);
      asm volatile("s_waitcnt vmcnt(8)" ::: "memory");
    } else {
      asm volatile("s_waitcnt vmcnt(0)" ::: "memory");
    }
    __builtin_amdgcn_s_barrier();
    __builtin_amdgcn_sched_barrier(0);
    const u16* pA = sA[cur];
    const u16* pB = sB[cur];
    #pragma unroll
    for (int ks=0;ks<2;ks++){
      bf16x8 aF[4], bF[4];
      #pragma unroll
      for (int mi=0;mi<4;mi++) aF[mi] = SWZ_FRAG(pA, wr+mi*16+ln, ks*4+quad);
      #pragma unroll
      for (int ni=0;ni<4;ni++) bF[ni] = SWZ_FRAG(pB, wc+ni*16+ln, ks*4+quad);
      #pragma unroll
      for (int mi=0;mi<4;mi++)
        #pragma unroll
        for (int ni=0;ni<4;ni++)
          acc[mi][ni] = __builtin_amdgcn_mfma_f32_16x16x32_bf16(aF[mi], bF[ni], acc[mi][ni], 0,0,0);
    }
    __builtin_amdgcn_sched_barrier(0);
    __builtin_amdgcn_s_barrier();
    __builtin_amdgcn_sched_barrier(0);
    cur ^= 1;
  }
  // epilogue: per-row (64-wide) LayerNorm, then scatter
  int sec = (n0 + wc) >> 6;          // 0..35, wave-uniform
  int which = sec / 12, h = sec - which*12;
  float hwv[4], hbv[4];
  #pragma unroll
  for (int ni=0;ni<4;ni++){ hwv[ni] = hw[ni*16+ln]; hbv[ni] = hb[ni*16+ln]; }
  #pragma unroll
  for (int mi=0;mi<4;mi++){
    #pragma unroll
    for (int r=0;r<4;r++){
      float s = acc[mi][0][r]+acc[mi][1][r]+acc[mi][2][r]+acc[mi][3][r];
      #pragma unroll
      for (int ofs=1; ofs<16; ofs<<=1) s += __shfl_xor(s, ofs);
      float mu = s * (1.0f/64.0f);
      float vv = 0.f;
      #pragma unroll
      for (int ni=0;ni<4;ni++){ float d = acc[mi][ni][r]-mu; vv += d*d; }
      #pragma unroll
      for (int ofs=1; ofs<16; ofs<<=1) vv += __shfl_xor(vv, ofs);
      float rstd = rsqrtf(vv*(1.0f/64.0f) + 1e-5f);
      int token = m0 + wr + mi*16 + quad*4 + r;
      int dir = token >> 13, bb = (token>>10)&7, n = token & 1023;
      size_t base = (size_t)dir*DIRSTRIDE + (size_t)bb*786432 + (size_t)h*65536;
      #pragma unroll
      for (int ni=0;ni<4;ni++){
        u16 y = f2bf((acc[mi][ni][r]-mu)*rstd*hwv[ni] + hbv[ni]);
        int hd = ni*16 + ln;
        if (which == 0)      q[base + (size_t)n*64 + hd] = y;
        else if (which == 1) k[base + (size_t)n*64 + hd] = y;
        else                 vt[base + (size_t)hd*1024 + n] = y;
      }
    }
  }
}

// ---------------- flash attention v7: async staging, dbuf, softmax diet --------
// (unchanged from r5: 134us, VALU-bound; GEMM pool is the bigger lever)
__global__ __launch_bounds__(256) void flash_kernel(const u16* __restrict__ qg,
    const u16* __restrict__ kg, const u16* __restrict__ vtg, u16* __restrict__ ctx)
{
  __shared__ __attribute__((aligned(16))) u16 sK[2][64*64];
  __shared__ __attribute__((aligned(16))) u16 sV[2][64*64];
  __shared__ __attribute__((aligned(16))) u16 sP[4*16*72];
  // XCD co-location: all 16 qt-blocks of one (b,h,dout) on the same XCD.
  int lin = (int)blockIdx.x + 16*((int)blockIdx.y + 96*(int)blockIdx.z);
  int x8 = lin & 7, jj = lin >> 3;
  int qt = jj & 15;
  int g  = x8 + 8*(jj >> 4);            // 0..191, bijective
  int dout = g & 1, bh = g >> 1;
  int b = bh/12, h = bh - b*12;
  size_t qbase = (size_t)(1-dout)*DIRSTRIDE + (size_t)b*786432 + (size_t)h*65536;
  size_t kbase = (size_t)dout*DIRSTRIDE + (size_t)b*786432 + (size_t)h*65536;
  int t = threadIdx.x;
  int w = t>>6, lane = t&63, ln = lane&15, quad = lane>>4;
  // Q fragment in registers for the whole loop: A[m=ln][k=quad*8+j (+32)]
  const u16* qp = qg + qbase + (size_t)(qt*64 + w*16 + ln)*64 + quad*8;
  bf16x8 aQ0 = *(const bf16x8*)qp;
  bf16x8 aQ1 = *(const bf16x8*)(qp + 32);
  bf16x8 vOne;
  #pragma unroll
  for (int j=0;j<8;j++) vOne[j] = (short)0x3F80;   // bf16 1.0
  f32x4 o[4];
  #pragma unroll
  for (int ni=0;ni<4;ni++) o[ni] = (f32x4){0.f,0.f,0.f,0.f};
  f32x4 oL = (f32x4){0.f,0.f,0.f,0.f};             // row-sums of P (softmax denom)
  u16* pw = &sP[w*16*72];
  const float cs = 0.18033688011112042f;   // 0.125 * log2(e)
  // prologue: stage tile kt=0 into buffer 0
  stage_tile64x64(kg  + kbase, 64, sK[0], w, lane);               // K rows: [kt*64+n][d]
  stage_tile64x64(vtg + kbase, 1024, sV[0], w, lane);             // V^T rows: [d][kt*64+n]
  __syncthreads();
  int cur = 0;
  for (int kt=0;kt<16;kt++){
    // stage next tile into the other buffer (async; drains at end-of-iter barrier)
    if (kt < 15){
      stage_tile64x64(kg  + kbase + (size_t)(kt+1)*4096, 64, sK[cur^1], w, lane);
      stage_tile64x64(vtg + kbase + (size_t)(kt+1)*64, 1024, sV[cur^1], w, lane);
    }
    const u16* sKc = sK[cur];
    const u16* sVc = sV[cur];
    // K fragments: B[n=kv=ni*16+ln][k=d=quad*8+j(+32)]
    bf16x8 bK[4][2], bV[4][2];
    #pragma unroll
    for (int ni=0;ni<4;ni++){
      int rr = ni*16 + ln;
      bK[ni][0] = SWZ_FRAG(sKc, rr, quad);
      bK[ni][1] = SWZ_FRAG(sKc, rr, 4+quad);
      // V fragments: B[n=d=ni*16+ln][k=kv-local=quad*8+j(+32)]
      bV[ni][0] = SWZ_FRAG(sVc, rr, quad);
      bV[ni][1] = SWZ_FRAG(sVc, rr, 4+quad);
    }
    f32x4 s[4];
    __builtin_amdgcn_s_setprio(1);
    #pragma unroll
    for (int ni=0;ni<4;ni++){
      s[ni] = (f32x4){0.f,0.f,0.f,0.f};
      s[ni] = __builtin_amdgcn_mfma_f32_16x16x32_bf16(aQ0, bK[ni][0], s[ni], 0,0,0);
      s[ni] = __builtin_amdgcn_mfma_f32_16x16x32_bf16(aQ1, bK[ni][1], s[ni], 0,0,0);
    }
    __builtin_amdgcn_s_setprio(0);
    // p = exp2(cs*s); bounded, no clamp; cheap half-up bf16 round
    #pragma unroll
    for (int ni=0;ni<4;ni++){
      #pragma unroll
      for (int r=0;r<4;r++){
        float p = exp2f(s[ni][r]*cs);
        pw[(quad*4+r)*72 + ni*16 + ln] = f2bf_fast(p);
      }
    }
    // NO barrier: pw is wave-private; compiler orders ds write->read via lgkmcnt
    bf16x8 aP0 = *(const bf16x8*)&pw[ln*72 + quad*8];
    bf16x8 aP1 = *(const bf16x8*)&pw[ln*72 + 32 + quad*8];
    __builtin_amdgcn_s_setprio(1);
    #pragma unroll
    for (int ni=0;ni<4;ni++){
      o[ni] = __builtin_amdgcn_mfma_f32_16x16x32_bf16(aP0, bV[ni][0], o[ni], 0,0,0);
      o[ni] = __builtin_amdgcn_mfma_f32_16x16x32_bf16(aP1, bV[ni][1], o[ni], 0,0,0);
    }
    oL = __builtin_amdgcn_mfma_f32_16x16x32_bf16(aP0, vOne, oL, 0,0,0);
    oL = __builtin_amdgcn_mfma_f32_16x16x32_bf16(aP1, vOne, oL, 0,0,0);
    __builtin_amdgcn_s_setprio(0);
    __syncthreads();          // single barrier/iter: next tile staged + readable
    cur ^= 1;
  }
  #pragma unroll
  for (int ni=0;ni<4;ni++){
    #pragma unroll
    for (int r=0;r<4;r++){
      int row = qt*64 + w*16 + quad*4 + r;
      float val = o[ni][r] / oL[r];
      ctx[((size_t)dout*8192 + (size_t)b*1024 + row)*768 + h*64 + ni*16 + ln] = f2bf(val);
    }
  }
}

// ---------------- launcher ----------------
// Workspace layout (bytes) — total 114,950,144 (~110 MiB); h1 f32 lives in d_out.
//   [0,          25165824)  xn bf16    (ln -> qkv gemm), then ctx bf16 (flash -> proj)
//   [25165824,   50331648)  q bf16     (qkv -> proj)
//       [0, 50331648)       g bf16 chunk scratch for MLP (after proj)
//   [50331648,   75497472)  k bf16     (qkv -> flash), then h1n bf16 (ln2 -> fc1)
//   [75497472,  100663296)  vt bf16    (qkv -> flash)
//   [100663296, 114819072)  bf16 weights (qkv,proj,fc1,fc2)
//   [114819072, 114950144)  norm1 mu/rstd f32[16384] each
extern "C" void kernel_launch(void* const* d_in, const int* in_sizes, int n_in,
                              void* d_out, int out_size, void* d_ws, size_t ws_size,
                              hipStream_t stream)
{
  const float* before = (const float*)d_in[0];
  const float* after  = (const float*)d_in[1];
  const float* n1w  = (const float*)d_in[2];
  const float* n1b  = (const float*)d_in[3];
  const float* qkvw = (const float*)d_in[4];
  const float* hlnw = (const float*)d_in[5];
  const float* hlnb = (const float*)d_in[6];
  const float* projw= (const float*)d_in[7];
  const float* projb= (const float*)d_in[8];
  const float* n2w  = (const float*)d_in[9];
  const float* n2b  = (const float*)d_in[10];
  const float* fc1w = (const float*)d_in[11];
  const float* fc1b = (const float*)d_in[12];
  const float* fc2w = (const float*)d_in[13];
  const float* fc2b = (const float*)d_in[14];

  const size_t REQUIRED = 114950144;
  if (ws_size < REQUIRED){
    // Diagnostic fallback: never touch d_ws; clean test failure instead of fault.
    zero_kernel<<<(out_size + 255)/256, 256, 0, stream>>>((float*)d_out, out_size);
    return;
  }

  char* ws = (char*)d_ws;
  u16* xn    = (u16*)(ws + 0);
  u16* ctxb  = (u16*)(ws + 0);            // reuse xn slot (xn dead after qkv gemm)
  u16* gbuf  = (u16*)(ws + 0);            // MLP chunk scratch (ctx+q dead by then)
  u16* qb    = (u16*)(ws + 25165824);
  u16* kb    = (u16*)(ws + 50331648);
  u16* h1n   = (u16*)(ws + 50331648);     // reuse k slot (k dead after flash)
  u16* vtb   = (u16*)(ws + 75497472);
  u16* wqkv  = (u16*)(ws + 100663296);
  u16* wproj = (u16*)(ws + 104202240);
  u16* wfc1  = (u16*)(ws + 105381888);
  u16* wfc2  = (u16*)(ws + 110100480);
  float* mu1  = (float*)(ws + 114819072);
  float* rs1  = (float*)(ws + 114884608);
  float* h1   = (float*)d_out;            // h1 f32 scratch lives in d_out
  float* outp = (float*)d_out;

  cvt_kernel<<<6912, 256, 0, stream>>>(qkvw, wqkv, 1769472);
  cvt_kernel<<<2304, 256, 0, stream>>>(projw, wproj, 589824);
  cvt_kernel<<<9216, 256, 0, stream>>>(fc1w, wfc1, 2359296);
  cvt_kernel<<<9216, 256, 0, stream>>>(fc2w, wfc2, 2359296);

  // 1) LN(before), LN(after) -> xn bf16 (+ stats for residual recompute)
  ln_kernel<<<16384, 256, 0, stream>>>(before, after, n1w, n1b, xn, mu1, rs1);
  // 2) qkv = xn @ qkv_w^T, fused per-head LN, scatter to q,k,v^T (xn dies here)
  gemm_qkv_kernel<<<dim3(18,128), 256, 0, stream>>>(xn, wqkv, hlnw, hlnb, qb, kb, vtb);
  // 3) cross attention; ctx overwrites xn slot (dirout0: q from after, k/v from before)
  flash_kernel<<<dim3(16,96,2), 256, 0, stream>>>(qb, kb, vtb, ctxb);
  // 4) h1 = ctx @ proj_w^T + proj_b + q_scrambled + LN(x) recomputed  (f32, into d_out)
  gemm_proj_kernel<<<dim3(6,128), 256, 0, stream>>>(ctxb, wproj, h1,
      projb, qb, before, after, n1w, n1b, mu1, rs1);
  // 5) h1n = LN(h1) bf16 (k slot)
  ln_kernel<<<16384, 256, 0, stream>>>(h1, h1 + (size_t)8192*768, n2w, n2b, h1n,
      nullptr, nullptr);
  // 6/7) MLP in two row-chunks of 8192 (g scratch = 50.3 MB in ctx+q slots)
  for (int c = 0; c < 2; c++){
    size_t off = (size_t)c * 8192 * 768;       // elements into (16384,768)
    gemm_kernel<2><<<dim3(24,64), 256, 0, stream>>>(h1n + off, wfc1, gbuf,
        fc1b, nullptr, 8192, 3072, 768);
    gemm_kernel<3><<<dim3(6,64), 256, 0, stream>>>(gbuf, wfc2, outp + off,
        fc2b, h1 + off, 8192, 768, 3072);
  }
}

// Round 8
// 648.233 us; speedup vs baseline: 1.1502x; 1.1123x over previous
//
#include <hip/hip_runtime.h>
#include <hip/hip_bf16.h>

typedef unsigned short u16;
typedef __attribute__((ext_vector_type(8))) short bf16x8;
typedef __attribute__((ext_vector_type(4))) float f32x4;

// Problem constants: B=8, N=1024, C=768, H=12, D=64, 3C=2304, HID=3072
// rows (both dirs stacked) = 16384; per-dir element count = 8*1024*768 = 6291456
#define DIRSTRIDE 6291456

__device__ __forceinline__ u16 f2bf(float x){
  __hip_bfloat16 h = __float2bfloat16(x);
  return *reinterpret_cast<u16*>(&h);
}
__device__ __forceinline__ float bf2f(u16 u){
  return __uint_as_float(((unsigned int)u) << 16);
}
// cheap bf16 round (half-up): valid for finite non-NaN; P>0 normals here.
__device__ __forceinline__ u16 f2bf_fast(float x){
  return (u16)((__float_as_uint(x) + 0x8000u) >> 16);
}

// XCD-aware block swizzle (T1): nwg%8==0 for all our GEMM grids; bijective.
// Consecutive remapped ids share the A row-panel -> same-XCD L2 reuse.
__device__ __forceinline__ void xcd_remap(int& bx, int& by){
  int gx = (int)gridDim.x;
  int lin = (int)blockIdx.x + gx*(int)blockIdx.y;
  int nwg8 = (gx*(int)gridDim.y) >> 3;
  int rl = (lin & 7)*nwg8 + (lin >> 3);
  bx = rl % gx; by = rl / gx;
}

// ---------------- fallback: zero d_out (diagnostic path if ws too small) -------
__global__ __launch_bounds__(256) void zero_kernel(float* __restrict__ p, int n){
  int i = blockIdx.x*256 + threadIdx.x;
  if (i < n) p[i] = 0.f;
}

// ---------------- fp32 -> bf16 weight conversion ----------------
__global__ __launch_bounds__(256) void cvt_kernel(const float* __restrict__ s,
                                                  u16* __restrict__ d, int n){
  int i = blockIdx.x*256 + threadIdx.x;
  if (i < n) d[i] = f2bf(s[i]);
}

// ---------------- LayerNorm over 768, two stacked sources -> bf16 ----------------
__global__ __launch_bounds__(256) void ln_kernel(const float* __restrict__ s0,
    const float* __restrict__ s1, const float* __restrict__ w,
    const float* __restrict__ b, u16* __restrict__ out,
    float* __restrict__ mu_out, float* __restrict__ rs_out){
  int r = blockIdx.x;
  const float* src = (r < 8192) ? (s0 + (size_t)r*768) : (s1 + (size_t)(r-8192)*768);
  int t = threadIdx.x;
  float v0 = src[t], v1 = src[t+256], v2 = src[t+512];
  __shared__ float red[4];
  float s = v0+v1+v2;
  #pragma unroll
  for (int o=32;o;o>>=1) s += __shfl_xor(s,o);
  if ((t&63)==0) red[t>>6] = s;
  __syncthreads();
  float mean = (red[0]+red[1]+red[2]+red[3]) * (1.0f/768.0f);
  float d0=v0-mean, d1=v1-mean, d2=v2-mean;
  float q = d0*d0+d1*d1+d2*d2;
  __syncthreads();
  #pragma unroll
  for (int o=32;o;o>>=1) q += __shfl_xor(q,o);
  if ((t&63)==0) red[t>>6] = q;
  __syncthreads();
  float var = (red[0]+red[1]+red[2]+red[3]) * (1.0f/768.0f);
  float rstd = rsqrtf(var + 1e-5f);
  if (mu_out && t == 0){ mu_out[r] = mean; rs_out[r] = rstd; }
  size_t base = (size_t)r*768;
  out[base+t]     = f2bf(d0*rstd*w[t]     + b[t]);
  out[base+t+256] = f2bf(d1*rstd*w[t+256] + b[t+256]);
  out[base+t+512] = f2bf(d2*rstd*w[t+512] + b[t+512]);
}

// ---------------- async staging: 128x64 u16 tile, XOR-swizzled ------------------
// T2 swizzle under global_load_lds (rule #21, both-sides-or-neither):
//   LDS dest is LINEAR (wave-uniform base + lane*16, m104 caveat).
//   The 16B chunk within each 128B row is XOR'd with (row&7) on the GLOBAL
//   source address; readers apply the same involution.
__device__ __forceinline__ void stage_tile64(const u16* g, size_t strideK, u16* lds,
                                             int w, int lane){
  #pragma unroll
  for (int i=0;i<4;i++){
    int row = w*32 + i*8 + (lane>>3);
    int cs  = (lane&7) ^ (row&7);            // pre-swizzled source chunk
    const u16* gp = g + (size_t)row*strideK + cs*8;
    __builtin_amdgcn_global_load_lds(
        (const __attribute__((address_space(1))) unsigned int*)gp,
        (__attribute__((address_space(3))) unsigned int*)(lds + (w*4+i)*512),
        16, 0, 0);
  }
}

// 64x64 u16 tile variant (8KB): wave w, instr i covers rows w*16+i*8..+8.
__device__ __forceinline__ void stage_tile64x64(const u16* g, size_t strideK,
                                                u16* lds, int w, int lane){
  #pragma unroll
  for (int i=0;i<2;i++){
    int row = w*16 + i*8 + (lane>>3);
    int cs  = (lane&7) ^ (row&7);            // pre-swizzled source chunk
    const u16* gp = g + (size_t)row*strideK + cs*8;
    __builtin_amdgcn_global_load_lds(
        (const __attribute__((address_space(1))) unsigned int*)gp,
        (__attribute__((address_space(3))) unsigned int*)(lds + (w*2+i)*512),
        16, 0, 0);
  }
}

// Fragment read address for logical (row r, k-chunk c) in a swizzled tile
// (row stride 64 u16): &tile[r*64 + (c ^ (r&7))*8]
#define SWZ_FRAG(tile, r, c) (*(const bf16x8*)&(tile)[(r)*64 + (((c) ^ ((r)&7)))*8])

// ---------------- bf16 MFMA GEMM core (128x128 tile, BK=64, swizzled LDS) -------
// r5-verified single-buffer structure (683us total): 2 barriers/iter; inter-block
// TLP (4+ blocks/CU) hides staging latency. Both dbuf attempts (r6/r7) regressed:
// 64KB LDS halves occupancy and loses more than intra-block overlap gains.
// EPI 2: bf16 out = gelu_exact(dot + bias[col])
// EPI 3: f32 out = dot + bias[col] + resF[flat]   (resF may alias Cout: same idx)
template<int EPI>
__global__ __launch_bounds__(256, 4) void gemm_kernel(
    const u16* __restrict__ A, const u16* __restrict__ W, void* Cout,
    const float* __restrict__ bias, const float* resF,
    int M, int N, int K)
{
  __shared__ __attribute__((aligned(16))) u16 sA[128*64];
  __shared__ __attribute__((aligned(16))) u16 sB[128*64];
  int t = threadIdx.x;
  int w = t>>6, lane = t&63, ln = lane&15, quad = lane>>4;
  int bx, by; xcd_remap(bx, by);
  int m0 = by*128, n0 = bx*128;
  int wr = (w>>1)*64, wc = (w&1)*64;
  f32x4 acc[4][4];
  #pragma unroll
  for (int mi=0;mi<4;mi++)
    #pragma unroll
    for (int ni=0;ni<4;ni++) acc[mi][ni] = (f32x4){0.f,0.f,0.f,0.f};
  int KB = K >> 6;
  for (int kb=0;kb<KB;kb++){
    __syncthreads();
    stage_tile64(A + (size_t)m0*K + kb*64, K, sA, w, lane);
    stage_tile64(W + (size_t)n0*K + kb*64, K, sB, w, lane);
    __syncthreads();
    #pragma unroll
    for (int ks=0;ks<2;ks++){
      bf16x8 aF[4], bF[4];
      #pragma unroll
      for (int mi=0;mi<4;mi++) aF[mi] = SWZ_FRAG(sA, wr+mi*16+ln, ks*4+quad);
      #pragma unroll
      for (int ni=0;ni<4;ni++) bF[ni] = SWZ_FRAG(sB, wc+ni*16+ln, ks*4+quad);
      #pragma unroll
      for (int mi=0;mi<4;mi++)
        #pragma unroll
        for (int ni=0;ni<4;ni++)
          acc[mi][ni] = __builtin_amdgcn_mfma_f32_16x16x32_bf16(aF[mi], bF[ni], acc[mi][ni], 0,0,0);
    }
  }
  #pragma unroll
  for (int mi=0;mi<4;mi++){
    #pragma unroll
    for (int ni=0;ni<4;ni++){
      #pragma unroll
      for (int r=0;r<4;r++){
        int row = m0 + wr + mi*16 + quad*4 + r;
        int col = n0 + wc + ni*16 + ln;
        size_t ridx = (size_t)row*N + col;
        float v = acc[mi][ni][r];
        if (EPI == 2){
          v += bias[col];
          v = 0.5f*v*(1.0f + erff(v*0.70710678118654752f));
          ((u16*)Cout)[ridx] = f2bf(v);
        } else {
          float rf = resF[ridx];          // may be same address as Cout[ridx]
          ((float*)Cout)[ridx] = v + bias[col] + rf;
        }
      }
    }
  }
}

// ---------------- fc2 GEMM: 128x64 tile for occupancy ---------------------------
// fc2 at 128x128 tiles had grid (6,64)=384 blocks = 1.5 blocks/CU: no TLP and a
// 2x tail imbalance -> the slowest GEMM (~180us for both calls). 128x64 tile
// doubles the grid to (12,64)=768 = 3 blocks/CU, LDS 24KB (6 blocks/CU allowed).
// Wave w: rows w*32..+31 (2 m-frags), all 64 cols (4 n-frags).
// out f32 = dot + bias[col] + resF[flat] (resF may alias Cout: same index).
__global__ __launch_bounds__(256, 4) void gemm_fc2_kernel(
    const u16* __restrict__ A, const u16* __restrict__ W, float* __restrict__ Cout,
    const float* __restrict__ bias, const float* resF)
{
  const int N = 768, K = 3072, KB = 48;
  __shared__ __attribute__((aligned(16))) u16 sA[128*64];
  __shared__ __attribute__((aligned(16))) u16 sB[64*64];
  int t = threadIdx.x;
  int w = t>>6, lane = t&63, ln = lane&15, quad = lane>>4;
  int bx, by; xcd_remap(bx, by);
  int m0 = by*128, n0 = bx*64;
  int wr = w*32;
  f32x4 acc[2][4];
  #pragma unroll
  for (int mi=0;mi<2;mi++)
    #pragma unroll
    for (int ni=0;ni<4;ni++) acc[mi][ni] = (f32x4){0.f,0.f,0.f,0.f};
  for (int kb=0;kb<KB;kb++){
    __syncthreads();
    stage_tile64(A + (size_t)m0*K + kb*64, K, sA, w, lane);
    stage_tile64x64(W + (size_t)n0*K + kb*64, K, sB, w, lane);
    __syncthreads();
    #pragma unroll
    for (int ks=0;ks<2;ks++){
      bf16x8 aF[2], bF[4];
      #pragma unroll
      for (int mi=0;mi<2;mi++) aF[mi] = SWZ_FRAG(sA, wr+mi*16+ln, ks*4+quad);
      #pragma unroll
      for (int ni=0;ni<4;ni++) bF[ni] = SWZ_FRAG(sB, ni*16+ln, ks*4+quad);
      #pragma unroll
      for (int mi=0;mi<2;mi++)
        #pragma unroll
        for (int ni=0;ni<4;ni++)
          acc[mi][ni] = __builtin_amdgcn_mfma_f32_16x16x32_bf16(aF[mi], bF[ni], acc[mi][ni], 0,0,0);
    }
  }
  #pragma unroll
  for (int mi=0;mi<2;mi++){
    #pragma unroll
    for (int ni=0;ni<4;ni++){
      #pragma unroll
      for (int r=0;r<4;r++){
        int row = m0 + wr + mi*16 + quad*4 + r;
        int col = n0 + ni*16 + ln;
        size_t ridx = (size_t)row*N + col;
        float rf = resF[ridx];            // may alias Cout[ridx]
        Cout[ridx] = acc[mi][ni][r] + bias[col] + rf;
      }
    }
  }
}

// ---------------- proj GEMM with fused residuals (r5 single-buffer core) --------
// h1 = ctx @ proj_w^T + proj_b + q_scrambled(opposite stream) + recomputed LN(x).
__global__ __launch_bounds__(256, 4) void gemm_proj_kernel(
    const u16* __restrict__ A, const u16* __restrict__ W, float* Cout,
    const float* __restrict__ bias, const u16* __restrict__ resQ,
    const float* __restrict__ before, const float* __restrict__ after,
    const float* __restrict__ n1w, const float* __restrict__ n1b,
    const float* __restrict__ mu, const float* __restrict__ rstd)
{
  const int K = 768, N = 768, KB = 12;
  __shared__ __attribute__((aligned(16))) u16 sA[128*64];
  __shared__ __attribute__((aligned(16))) u16 sB[128*64];
  int t = threadIdx.x;
  int w = t>>6, lane = t&63, ln = lane&15, quad = lane>>4;
  int bx, by; xcd_remap(bx, by);
  int m0 = by*128, n0 = bx*128;
  int wr = (w>>1)*64, wc = (w&1)*64;
  f32x4 acc[4][4];
  #pragma unroll
  for (int mi=0;mi<4;mi++)
    #pragma unroll
    for (int ni=0;ni<4;ni++) acc[mi][ni] = (f32x4){0.f,0.f,0.f,0.f};
  for (int kb=0;kb<KB;kb++){
    __syncthreads();
    stage_tile64(A + (size_t)m0*K + kb*64, K, sA, w, lane);
    stage_tile64(W + (size_t)n0*K + kb*64, K, sB, w, lane);
    __syncthreads();
    #pragma unroll
    for (int ks=0;ks<2;ks++){
      bf16x8 aF[4], bF[4];
      #pragma unroll
      for (int mi=0;mi<4;mi++) aF[mi] = SWZ_FRAG(sA, wr+mi*16+ln, ks*4+quad);
      #pragma unroll
      for (int ni=0;ni<4;ni++) bF[ni] = SWZ_FRAG(sB, wc+ni*16+ln, ks*4+quad);
      #pragma unroll
      for (int mi=0;mi<4;mi++)
        #pragma unroll
        for (int ni=0;ni<4;ni++)
          acc[mi][ni] = __builtin_amdgcn_mfma_f32_16x16x32_bf16(aF[mi], bF[ni], acc[mi][ni], 0,0,0);
    }
  }
  #pragma unroll
  for (int mi=0;mi<4;mi++){
    #pragma unroll
    for (int ni=0;ni<4;ni++){
      #pragma unroll
      for (int r=0;r<4;r++){
        int row = m0 + wr + mi*16 + quad*4 + r;
        int col = n0 + wc + ni*16 + ln;
        size_t ridx = (size_t)row*N + col;
        int dirout = row >> 13;
        int rem = row & 8191;
        // faithful q.reshape(B,N,H*D): flat per-batch add of (H,N,D) buffer;
        // q comes from the OPPOSITE stream (context_b uses q_a and vice versa)
        size_t qidx = (size_t)(1-dirout)*DIRSTRIDE + (size_t)rem*768 + col;
        const float* src = dirout ? after : before;
        float xr = (src[(size_t)rem*768 + col] - mu[row]) * rstd[row] * n1w[col] + n1b[col];
        Cout[ridx] = acc[mi][ni][r] + bias[col] + bf2f(resQ[qidx]) + xr;
      }
    }
  }
}

// ---------------- qkv GEMM, per-head LN epilogue (r5 single-buffer core) --------
__global__ __launch_bounds__(256, 4) void gemm_qkv_kernel(
    const u16* __restrict__ A, const u16* __restrict__ W,
    const float* __restrict__ hw, const float* __restrict__ hb,
    u16* __restrict__ q, u16* __restrict__ k, u16* __restrict__ vt)
{
  const int K = 768, KB = 12;
  __shared__ __attribute__((aligned(16))) u16 sA[128*64];
  __shared__ __attribute__((aligned(16))) u16 sB[128*64];
  int t = threadIdx.x;
  int w = t>>6, lane = t&63, ln = lane&15, quad = lane>>4;
  int bx, by; xcd_remap(bx, by);
  int m0 = by*128, n0 = bx*128;
  int wr = (w>>1)*64, wc = (w&1)*64;
  f32x4 acc[4][4];
  #pragma unroll
  for (int mi=0;mi<4;mi++)
    #pragma unroll
    for (int ni=0;ni<4;ni++) acc[mi][ni] = (f32x4){0.f,0.f,0.f,0.f};
  for (int kb=0;kb<KB;kb++){
    __syncthreads();
    stage_tile64(A + (size_t)m0*K + kb*64, K, sA, w, lane);
    stage_tile64(W + (size_t)n0*K + kb*64, K, sB, w, lane);
    __syncthreads();
    #pragma unroll
    for (int ks=0;ks<2;ks++){
      bf16x8 aF[4], bF[4];
      #pragma unroll
      for (int mi=0;mi<4;mi++) aF[mi] = SWZ_FRAG(sA, wr+mi*16+ln, ks*4+quad);
      #pragma unroll
      for (int ni=0;ni<4;ni++) bF[ni] = SWZ_FRAG(sB, wc+ni*16+ln, ks*4+quad);
      #pragma unroll
      for (int mi=0;mi<4;mi++)
        #pragma unroll
        for (int ni=0;ni<4;ni++)
          acc[mi][ni] = __builtin_amdgcn_mfma_f32_16x16x32_bf16(aF[mi], bF[ni], acc[mi][ni], 0,0,0);
    }
  }
  // epilogue: per-row (64-wide) LayerNorm, then scatter
  int sec = (n0 + wc) >> 6;          // 0..35, wave-uniform
  int which = sec / 12, h = sec - which*12;
  float hwv[4], hbv[4];
  #pragma unroll
  for (int ni=0;ni<4;ni++){ hwv[ni] = hw[ni*16+ln]; hbv[ni] = hb[ni*16+ln]; }
  #pragma unroll
  for (int mi=0;mi<4;mi++){
    #pragma unroll
    for (int r=0;r<4;r++){
      float s = acc[mi][0][r]+acc[mi][1][r]+acc[mi][2][r]+acc[mi][3][r];
      #pragma unroll
      for (int ofs=1; ofs<16; ofs<<=1) s += __shfl_xor(s, ofs);
      float mu = s * (1.0f/64.0f);
      float vv = 0.f;
      #pragma unroll
      for (int ni=0;ni<4;ni++){ float d = acc[mi][ni][r]-mu; vv += d*d; }
      #pragma unroll
      for (int ofs=1; ofs<16; ofs<<=1) vv += __shfl_xor(vv, ofs);
      float rstd = rsqrtf(vv*(1.0f/64.0f) + 1e-5f);
      int token = m0 + wr + mi*16 + quad*4 + r;
      int dir = token >> 13, bb = (token>>10)&7, n = token & 1023;
      size_t base = (size_t)dir*DIRSTRIDE + (size_t)bb*786432 + (size_t)h*65536;
      #pragma unroll
      for (int ni=0;ni<4;ni++){
        u16 y = f2bf((acc[mi][ni][r]-mu)*rstd*hwv[ni] + hbv[ni]);
        int hd = ni*16 + ln;
        if (which == 0)      q[base + (size_t)n*64 + hd] = y;
        else if (which == 1) k[base + (size_t)n*64 + hd] = y;
        else                 vt[base + (size_t)hd*1024 + n] = y;
      }
    }
  }
}

// ---------------- flash attention v7: async staging, dbuf, softmax diet --------
// (unchanged: ~129us, VALU-bound)
__global__ __launch_bounds__(256) void flash_kernel(const u16* __restrict__ qg,
    const u16* __restrict__ kg, const u16* __restrict__ vtg, u16* __restrict__ ctx)
{
  __shared__ __attribute__((aligned(16))) u16 sK[2][64*64];
  __shared__ __attribute__((aligned(16))) u16 sV[2][64*64];
  __shared__ __attribute__((aligned(16))) u16 sP[4*16*72];
  // XCD co-location: all 16 qt-blocks of one (b,h,dout) on the same XCD.
  int lin = (int)blockIdx.x + 16*((int)blockIdx.y + 96*(int)blockIdx.z);
  int x8 = lin & 7, jj = lin >> 3;
  int qt = jj & 15;
  int g  = x8 + 8*(jj >> 4);            // 0..191, bijective
  int dout = g & 1, bh = g >> 1;
  int b = bh/12, h = bh - b*12;
  size_t qbase = (size_t)(1-dout)*DIRSTRIDE + (size_t)b*786432 + (size_t)h*65536;
  size_t kbase = (size_t)dout*DIRSTRIDE + (size_t)b*786432 + (size_t)h*65536;
  int t = threadIdx.x;
  int w = t>>6, lane = t&63, ln = lane&15, quad = lane>>4;
  // Q fragment in registers for the whole loop: A[m=ln][k=quad*8+j (+32)]
  const u16* qp = qg + qbase + (size_t)(qt*64 + w*16 + ln)*64 + quad*8;
  bf16x8 aQ0 = *(const bf16x8*)qp;
  bf16x8 aQ1 = *(const bf16x8*)(qp + 32);
  bf16x8 vOne;
  #pragma unroll
  for (int j=0;j<8;j++) vOne[j] = (short)0x3F80;   // bf16 1.0
  f32x4 o[4];
  #pragma unroll
  for (int ni=0;ni<4;ni++) o[ni] = (f32x4){0.f,0.f,0.f,0.f};
  f32x4 oL = (f32x4){0.f,0.f,0.f,0.f};             // row-sums of P (softmax denom)
  u16* pw = &sP[w*16*72];
  const float cs = 0.18033688011112042f;   // 0.125 * log2(e)
  // prologue: stage tile kt=0 into buffer 0
  stage_tile64x64(kg  + kbase, 64, sK[0], w, lane);               // K rows: [kt*64+n][d]
  stage_tile64x64(vtg + kbase, 1024, sV[0], w, lane);             // V^T rows: [d][kt*64+n]
  __syncthreads();
  int cur = 0;
  for (int kt=0;kt<16;kt++){
    // stage next tile into the other buffer (async; drains at end-of-iter barrier)
    if (kt < 15){
      stage_tile64x64(kg  + kbase + (size_t)(kt+1)*4096, 64, sK[cur^1], w, lane);
      stage_tile64x64(vtg + kbase + (size_t)(kt+1)*64, 1024, sV[cur^1], w, lane);
    }
    const u16* sKc = sK[cur];
    const u16* sVc = sV[cur];
    // K fragments: B[n=kv=ni*16+ln][k=d=quad*8+j(+32)]
    bf16x8 bK[4][2], bV[4][2];
    #pragma unroll
    for (int ni=0;ni<4;ni++){
      int rr = ni*16 + ln;
      bK[ni][0] = SWZ_FRAG(sKc, rr, quad);
      bK[ni][1] = SWZ_FRAG(sKc, rr, 4+quad);
      // V fragments: B[n=d=ni*16+ln][k=kv-local=quad*8+j(+32)]
      bV[ni][0] = SWZ_FRAG(sVc, rr, quad);
      bV[ni][1] = SWZ_FRAG(sVc, rr, 4+quad);
    }
    f32x4 s[4];
    __builtin_amdgcn_s_setprio(1);
    #pragma unroll
    for (int ni=0;ni<4;ni++){
      s[ni] = (f32x4){0.f,0.f,0.f,0.f};
      s[ni] = __builtin_amdgcn_mfma_f32_16x16x32_bf16(aQ0, bK[ni][0], s[ni], 0,0,0);
      s[ni] = __builtin_amdgcn_mfma_f32_16x16x32_bf16(aQ1, bK[ni][1], s[ni], 0,0,0);
    }
    __builtin_amdgcn_s_setprio(0);
    // p = exp2(cs*s); bounded, no clamp; cheap half-up bf16 round
    #pragma unroll
    for (int ni=0;ni<4;ni++){
      #pragma unroll
      for (int r=0;r<4;r++){
        float p = exp2f(s[ni][r]*cs);
        pw[(quad*4+r)*72 + ni*16 + ln] = f2bf_fast(p);
      }
    }
    // NO barrier: pw is wave-private; compiler orders ds write->read via lgkmcnt
    bf16x8 aP0 = *(const bf16x8*)&pw[ln*72 + quad*8];
    bf16x8 aP1 = *(const bf16x8*)&pw[ln*72 + 32 + quad*8];
    __builtin_amdgcn_s_setprio(1);
    #pragma unroll
    for (int ni=0;ni<4;ni++){
      o[ni] = __builtin_amdgcn_mfma_f32_16x16x32_bf16(aP0, bV[ni][0], o[ni], 0,0,0);
      o[ni] = __builtin_amdgcn_mfma_f32_16x16x32_bf16(aP1, bV[ni][1], o[ni], 0,0,0);
    }
    oL = __builtin_amdgcn_mfma_f32_16x16x32_bf16(aP0, vOne, oL, 0,0,0);
    oL = __builtin_amdgcn_mfma_f32_16x16x32_bf16(aP1, vOne, oL, 0,0,0);
    __builtin_amdgcn_s_setprio(0);
    __syncthreads();          // single barrier/iter: next tile staged + readable
    cur ^= 1;
  }
  #pragma unroll
  for (int ni=0;ni<4;ni++){
    #pragma unroll
    for (int r=0;r<4;r++){
      int row = qt*64 + w*16 + quad*4 + r;
      float val = o[ni][r] / oL[r];
      ctx[((size_t)dout*8192 + (size_t)b*1024 + row)*768 + h*64 + ni*16 + ln] = f2bf(val);
    }
  }
}

// ---------------- launcher ----------------
// Workspace layout (bytes) — total 114,950,144 (~110 MiB); h1 f32 lives in d_out.
//   [0,          25165824)  xn bf16    (ln -> qkv gemm), then ctx bf16 (flash -> proj)
//   [25165824,   50331648)  q bf16     (qkv -> proj)
//       [0, 50331648)       g bf16 chunk scratch for MLP (after proj)
//   [50331648,   75497472)  k bf16     (qkv -> flash), then h1n bf16 (ln2 -> fc1)
//   [75497472,  100663296)  vt bf16    (qkv -> flash)
//   [100663296, 114819072)  bf16 weights (qkv,proj,fc1,fc2)
//   [114819072, 114950144)  norm1 mu/rstd f32[16384] each
extern "C" void kernel_launch(void* const* d_in, const int* in_sizes, int n_in,
                              void* d_out, int out_size, void* d_ws, size_t ws_size,
                              hipStream_t stream)
{
  const float* before = (const float*)d_in[0];
  const float* after  = (const float*)d_in[1];
  const float* n1w  = (const float*)d_in[2];
  const float* n1b  = (const float*)d_in[3];
  const float* qkvw = (const float*)d_in[4];
  const float* hlnw = (const float*)d_in[5];
  const float* hlnb = (const float*)d_in[6];
  const float* projw= (const float*)d_in[7];
  const float* projb= (const float*)d_in[8];
  const float* n2w  = (const float*)d_in[9];
  const float* n2b  = (const float*)d_in[10];
  const float* fc1w = (const float*)d_in[11];
  const float* fc1b = (const float*)d_in[12];
  const float* fc2w = (const float*)d_in[13];
  const float* fc2b = (const float*)d_in[14];

  const size_t REQUIRED = 114950144;
  if (ws_size < REQUIRED){
    // Diagnostic fallback: never touch d_ws; clean test failure instead of fault.
    zero_kernel<<<(out_size + 255)/256, 256, 0, stream>>>((float*)d_out, out_size);
    return;
  }

  char* ws = (char*)d_ws;
  u16* xn    = (u16*)(ws + 0);
  u16* ctxb  = (u16*)(ws + 0);            // reuse xn slot (xn dead after qkv gemm)
  u16* gbuf  = (u16*)(ws + 0);            // MLP chunk scratch (ctx+q dead by then)
  u16* qb    = (u16*)(ws + 25165824);
  u16* kb    = (u16*)(ws + 50331648);
  u16* h1n   = (u16*)(ws + 50331648);     // reuse k slot (k dead after flash)
  u16* vtb   = (u16*)(ws + 75497472);
  u16* wqkv  = (u16*)(ws + 100663296);
  u16* wproj = (u16*)(ws + 104202240);
  u16* wfc1  = (u16*)(ws + 105381888);
  u16* wfc2  = (u16*)(ws + 110100480);
  float* mu1  = (float*)(ws + 114819072);
  float* rs1  = (float*)(ws + 114884608);
  float* h1   = (float*)d_out;            // h1 f32 scratch lives in d_out
  float* outp = (float*)d_out;

  cvt_kernel<<<6912, 256, 0, stream>>>(qkvw, wqkv, 1769472);
  cvt_kernel<<<2304, 256, 0, stream>>>(projw, wproj, 589824);
  cvt_kernel<<<9216, 256, 0, stream>>>(fc1w, wfc1, 2359296);
  cvt_kernel<<<9216, 256, 0, stream>>>(fc2w, wfc2, 2359296);

  // 1) LN(before), LN(after) -> xn bf16 (+ stats for residual recompute)
  ln_kernel<<<16384, 256, 0, stream>>>(before, after, n1w, n1b, xn, mu1, rs1);
  // 2) qkv = xn @ qkv_w^T, fused per-head LN, scatter to q,k,v^T (xn dies here)
  gemm_qkv_kernel<<<dim3(18,128), 256, 0, stream>>>(xn, wqkv, hlnw, hlnb, qb, kb, vtb);
  // 3) cross attention; ctx overwrites xn slot (dirout0: q from after, k/v from before)
  flash_kernel<<<dim3(16,96,2), 256, 0, stream>>>(qb, kb, vtb, ctxb);
  // 4) h1 = ctx @ proj_w^T + proj_b + q_scrambled + LN(x) recomputed  (f32, into d_out)
  gemm_proj_kernel<<<dim3(6,128), 256, 0, stream>>>(ctxb, wproj, h1,
      projb, qb, before, after, n1w, n1b, mu1, rs1);
  // 5) h1n = LN(h1) bf16 (k slot)
  ln_kernel<<<16384, 256, 0, stream>>>(h1, h1 + (size_t)8192*768, n2w, n2b, h1n,
      nullptr, nullptr);
  // 6/7) MLP in two row-chunks of 8192 (g scratch = 50.3 MB in ctx+q slots)
  for (int c = 0; c < 2; c++){
    size_t off = (size_t)c * 8192 * 768;       // elements into (16384,768)
    gemm_kernel<2><<<dim3(24,64), 256, 0, stream>>>(h1n + off, wfc1, gbuf,
        fc1b, nullptr, 8192, 3072, 768);
    gemm_fc2_kernel<<<dim3(12,64), 256, 0, stream>>>(gbuf, wfc2, outp + off,
        fc2b, h1 + off);
  }
}

// Round 9
// 617.278 us; speedup vs baseline: 1.2078x; 1.0501x over previous
//
#include <hip/hip_runtime.h>
#include <hip/hip_bf16.h>

typedef unsigned short u16;
typedef __attribute__((ext_vector_type(8))) short bf16x8;
typedef __attribute__((ext_vector_type(4))) float f32x4;

// Problem constants: B=8, N=1024, C=768, H=12, D=64, 3C=2304, HID=3072
// rows (both dirs stacked) = 16384; per-dir element count = 8*1024*768 = 6291456
#define DIRSTRIDE 6291456

__device__ __forceinline__ u16 f2bf(float x){
  __hip_bfloat16 h = __float2bfloat16(x);
  return *reinterpret_cast<u16*>(&h);
}
__device__ __forceinline__ float bf2f(u16 u){
  return __uint_as_float(((unsigned int)u) << 16);
}
// cheap bf16 round (half-up): valid for finite non-NaN; P>0 normals here.
__device__ __forceinline__ u16 f2bf_fast(float x){
  return (u16)((__float_as_uint(x) + 0x8000u) >> 16);
}

// XCD-aware block swizzle (T1): nwg%8==0 for all our GEMM grids; bijective.
// Consecutive remapped ids share the A row-panel -> same-XCD L2 reuse.
__device__ __forceinline__ void xcd_remap(int& bx, int& by){
  int gx = (int)gridDim.x;
  int lin = (int)blockIdx.x + gx*(int)blockIdx.y;
  int nwg8 = (gx*(int)gridDim.y) >> 3;
  int rl = (lin & 7)*nwg8 + (lin >> 3);
  bx = rl % gx; by = rl / gx;
}

// ---------------- fallback: zero d_out (diagnostic path if ws too small) -------
__global__ __launch_bounds__(256) void zero_kernel(float* __restrict__ p, int n){
  int i = blockIdx.x*256 + threadIdx.x;
  if (i < n) p[i] = 0.f;
}

// ---------------- fp32 -> bf16 weight conversion ----------------
__global__ __launch_bounds__(256) void cvt_kernel(const float* __restrict__ s,
                                                  u16* __restrict__ d, int n){
  int i = blockIdx.x*256 + threadIdx.x;
  if (i < n) d[i] = f2bf(s[i]);
}

// ---------------- LayerNorm over 768, two stacked sources -> bf16 ----------------
__global__ __launch_bounds__(256) void ln_kernel(const float* __restrict__ s0,
    const float* __restrict__ s1, const float* __restrict__ w,
    const float* __restrict__ b, u16* __restrict__ out,
    float* __restrict__ mu_out, float* __restrict__ rs_out){
  int r = blockIdx.x;
  const float* src = (r < 8192) ? (s0 + (size_t)r*768) : (s1 + (size_t)(r-8192)*768);
  int t = threadIdx.x;
  float v0 = src[t], v1 = src[t+256], v2 = src[t+512];
  __shared__ float red[4];
  float s = v0+v1+v2;
  #pragma unroll
  for (int o=32;o;o>>=1) s += __shfl_xor(s,o);
  if ((t&63)==0) red[t>>6] = s;
  __syncthreads();
  float mean = (red[0]+red[1]+red[2]+red[3]) * (1.0f/768.0f);
  float d0=v0-mean, d1=v1-mean, d2=v2-mean;
  float q = d0*d0+d1*d1+d2*d2;
  __syncthreads();
  #pragma unroll
  for (int o=32;o;o>>=1) q += __shfl_xor(q,o);
  if ((t&63)==0) red[t>>6] = q;
  __syncthreads();
  float var = (red[0]+red[1]+red[2]+red[3]) * (1.0f/768.0f);
  float rstd = rsqrtf(var + 1e-5f);
  if (mu_out && t == 0){ mu_out[r] = mean; rs_out[r] = rstd; }
  size_t base = (size_t)r*768;
  out[base+t]     = f2bf(d0*rstd*w[t]     + b[t]);
  out[base+t+256] = f2bf(d1*rstd*w[t+256] + b[t+256]);
  out[base+t+512] = f2bf(d2*rstd*w[t+512] + b[t+512]);
}

// ---------------- async staging: 128x64 u16 tile, XOR-swizzled ------------------
// T2 swizzle under global_load_lds (rule #21, both-sides-or-neither):
//   LDS dest is LINEAR (wave-uniform base + lane*16, m104 caveat).
//   The 16B chunk within each 128B row is XOR'd with (row&7) on the GLOBAL
//   source address; readers apply the same involution.
__device__ __forceinline__ void stage_tile64(const u16* g, size_t strideK, u16* lds,
                                             int w, int lane){
  #pragma unroll
  for (int i=0;i<4;i++){
    int row = w*32 + i*8 + (lane>>3);
    int cs  = (lane&7) ^ (row&7);            // pre-swizzled source chunk
    const u16* gp = g + (size_t)row*strideK + cs*8;
    __builtin_amdgcn_global_load_lds(
        (const __attribute__((address_space(1))) unsigned int*)gp,
        (__attribute__((address_space(3))) unsigned int*)(lds + (w*4+i)*512),
        16, 0, 0);
  }
}

// 64x64 u16 tile variant (8KB): wave w, instr i covers rows w*16+i*8..+8.
__device__ __forceinline__ void stage_tile64x64(const u16* g, size_t strideK,
                                                u16* lds, int w, int lane){
  #pragma unroll
  for (int i=0;i<2;i++){
    int row = w*16 + i*8 + (lane>>3);
    int cs  = (lane&7) ^ (row&7);            // pre-swizzled source chunk
    const u16* gp = g + (size_t)row*strideK + cs*8;
    __builtin_amdgcn_global_load_lds(
        (const __attribute__((address_space(1))) unsigned int*)gp,
        (__attribute__((address_space(3))) unsigned int*)(lds + (w*2+i)*512),
        16, 0, 0);
  }
}

// Fragment read address for logical (row r, k-chunk c) in a swizzled tile
// (row stride 64 u16): &tile[r*64 + (c ^ (r&7))*8]
#define SWZ_FRAG(tile, r, c) (*(const bf16x8*)&(tile)[(r)*64 + (((c) ^ ((r)&7)))*8])

// ---------------- bf16 MFMA GEMM core (128x128 tile, BK=64, swizzled LDS) -------
// r5-verified single-buffer structure: 2 barriers/iter; inter-block TLP
// (4+ blocks/CU) hides staging latency. Both dbuf attempts (r6/r7) regressed.
// EPI 2: bf16 out = gelu_exact(dot + bias[col])
// EPI 3: f32 out = dot + bias[col] + resF[flat]   (resF may alias Cout: same idx)
template<int EPI>
__global__ __launch_bounds__(256, 4) void gemm_kernel(
    const u16* __restrict__ A, const u16* __restrict__ W, void* Cout,
    const float* __restrict__ bias, const float* resF,
    int M, int N, int K)
{
  __shared__ __attribute__((aligned(16))) u16 sA[128*64];
  __shared__ __attribute__((aligned(16))) u16 sB[128*64];
  int t = threadIdx.x;
  int w = t>>6, lane = t&63, ln = lane&15, quad = lane>>4;
  int bx, by; xcd_remap(bx, by);
  int m0 = by*128, n0 = bx*128;
  int wr = (w>>1)*64, wc = (w&1)*64;
  f32x4 acc[4][4];
  #pragma unroll
  for (int mi=0;mi<4;mi++)
    #pragma unroll
    for (int ni=0;ni<4;ni++) acc[mi][ni] = (f32x4){0.f,0.f,0.f,0.f};
  int KB = K >> 6;
  for (int kb=0;kb<KB;kb++){
    __syncthreads();
    stage_tile64(A + (size_t)m0*K + kb*64, K, sA, w, lane);
    stage_tile64(W + (size_t)n0*K + kb*64, K, sB, w, lane);
    __syncthreads();
    #pragma unroll
    for (int ks=0;ks<2;ks++){
      bf16x8 aF[4], bF[4];
      #pragma unroll
      for (int mi=0;mi<4;mi++) aF[mi] = SWZ_FRAG(sA, wr+mi*16+ln, ks*4+quad);
      #pragma unroll
      for (int ni=0;ni<4;ni++) bF[ni] = SWZ_FRAG(sB, wc+ni*16+ln, ks*4+quad);
      #pragma unroll
      for (int mi=0;mi<4;mi++)
        #pragma unroll
        for (int ni=0;ni<4;ni++)
          acc[mi][ni] = __builtin_amdgcn_mfma_f32_16x16x32_bf16(aF[mi], bF[ni], acc[mi][ni], 0,0,0);
    }
  }
  #pragma unroll
  for (int mi=0;mi<4;mi++){
    #pragma unroll
    for (int ni=0;ni<4;ni++){
      #pragma unroll
      for (int r=0;r<4;r++){
        int row = m0 + wr + mi*16 + quad*4 + r;
        int col = n0 + wc + ni*16 + ln;
        size_t ridx = (size_t)row*N + col;
        float v = acc[mi][ni][r];
        if (EPI == 2){
          v += bias[col];
          v = 0.5f*v*(1.0f + erff(v*0.70710678118654752f));
          ((u16*)Cout)[ridx] = f2bf(v);
        } else {
          float rf = resF[ridx];          // may be same address as Cout[ridx]
          ((float*)Cout)[ridx] = v + bias[col] + rf;
        }
      }
    }
  }
}

// ---------------- fc2 GEMM: 128x64 tile for occupancy ---------------------------
// fc2 at 128x128 tiles: grid (6,64)=384 blocks = 1.5/CU -> latency-starved.
// 128x64 tile: grid (12,64)=768 = 3/CU, LDS 24KB.
__global__ __launch_bounds__(256, 4) void gemm_fc2_kernel(
    const u16* __restrict__ A, const u16* __restrict__ W, float* __restrict__ Cout,
    const float* __restrict__ bias, const float* resF)
{
  const int N = 768, K = 3072, KB = 48;
  __shared__ __attribute__((aligned(16))) u16 sA[128*64];
  __shared__ __attribute__((aligned(16))) u16 sB[64*64];
  int t = threadIdx.x;
  int w = t>>6, lane = t&63, ln = lane&15, quad = lane>>4;
  int bx, by; xcd_remap(bx, by);
  int m0 = by*128, n0 = bx*64;
  int wr = w*32;
  f32x4 acc[2][4];
  #pragma unroll
  for (int mi=0;mi<2;mi++)
    #pragma unroll
    for (int ni=0;ni<4;ni++) acc[mi][ni] = (f32x4){0.f,0.f,0.f,0.f};
  for (int kb=0;kb<KB;kb++){
    __syncthreads();
    stage_tile64(A + (size_t)m0*K + kb*64, K, sA, w, lane);
    stage_tile64x64(W + (size_t)n0*K + kb*64, K, sB, w, lane);
    __syncthreads();
    #pragma unroll
    for (int ks=0;ks<2;ks++){
      bf16x8 aF[2], bF[4];
      #pragma unroll
      for (int mi=0;mi<2;mi++) aF[mi] = SWZ_FRAG(sA, wr+mi*16+ln, ks*4+quad);
      #pragma unroll
      for (int ni=0;ni<4;ni++) bF[ni] = SWZ_FRAG(sB, ni*16+ln, ks*4+quad);
      #pragma unroll
      for (int mi=0;mi<2;mi++)
        #pragma unroll
        for (int ni=0;ni<4;ni++)
          acc[mi][ni] = __builtin_amdgcn_mfma_f32_16x16x32_bf16(aF[mi], bF[ni], acc[mi][ni], 0,0,0);
    }
  }
  #pragma unroll
  for (int mi=0;mi<2;mi++){
    #pragma unroll
    for (int ni=0;ni<4;ni++){
      #pragma unroll
      for (int r=0;r<4;r++){
        int row = m0 + wr + mi*16 + quad*4 + r;
        int col = n0 + ni*16 + ln;
        size_t ridx = (size_t)row*N + col;
        float rf = resF[ridx];            // may alias Cout[ridx]
        Cout[ridx] = acc[mi][ni][r] + bias[col] + rf;
      }
    }
  }
}

// ---------------- proj GEMM with fused residuals (r5 single-buffer core) --------
// h1 = ctx @ proj_w^T + proj_b + q_scrambled(opposite stream) + recomputed LN(x).
__global__ __launch_bounds__(256, 4) void gemm_proj_kernel(
    const u16* __restrict__ A, const u16* __restrict__ W, float* Cout,
    const float* __restrict__ bias, const u16* __restrict__ resQ,
    const float* __restrict__ before, const float* __restrict__ after,
    const float* __restrict__ n1w, const float* __restrict__ n1b,
    const float* __restrict__ mu, const float* __restrict__ rstd)
{
  const int K = 768, N = 768, KB = 12;
  __shared__ __attribute__((aligned(16))) u16 sA[128*64];
  __shared__ __attribute__((aligned(16))) u16 sB[128*64];
  int t = threadIdx.x;
  int w = t>>6, lane = t&63, ln = lane&15, quad = lane>>4;
  int bx, by; xcd_remap(bx, by);
  int m0 = by*128, n0 = bx*128;
  int wr = (w>>1)*64, wc = (w&1)*64;
  f32x4 acc[4][4];
  #pragma unroll
  for (int mi=0;mi<4;mi++)
    #pragma unroll
    for (int ni=0;ni<4;ni++) acc[mi][ni] = (f32x4){0.f,0.f,0.f,0.f};
  for (int kb=0;kb<KB;kb++){
    __syncthreads();
    stage_tile64(A + (size_t)m0*K + kb*64, K, sA, w, lane);
    stage_tile64(W + (size_t)n0*K + kb*64, K, sB, w, lane);
    __syncthreads();
    #pragma unroll
    for (int ks=0;ks<2;ks++){
      bf16x8 aF[4], bF[4];
      #pragma unroll
      for (int mi=0;mi<4;mi++) aF[mi] = SWZ_FRAG(sA, wr+mi*16+ln, ks*4+quad);
      #pragma unroll
      for (int ni=0;ni<4;ni++) bF[ni] = SWZ_FRAG(sB, wc+ni*16+ln, ks*4+quad);
      #pragma unroll
      for (int mi=0;mi<4;mi++)
        #pragma unroll
        for (int ni=0;ni<4;ni++)
          acc[mi][ni] = __builtin_amdgcn_mfma_f32_16x16x32_bf16(aF[mi], bF[ni], acc[mi][ni], 0,0,0);
    }
  }
  #pragma unroll
  for (int mi=0;mi<4;mi++){
    #pragma unroll
    for (int ni=0;ni<4;ni++){
      #pragma unroll
      for (int r=0;r<4;r++){
        int row = m0 + wr + mi*16 + quad*4 + r;
        int col = n0 + wc + ni*16 + ln;
        size_t ridx = (size_t)row*N + col;
        int dirout = row >> 13;
        int rem = row & 8191;
        // faithful q.reshape(B,N,H*D): flat per-batch add of (H,N,D) buffer;
        // q comes from the OPPOSITE stream (context_b uses q_a and vice versa)
        size_t qidx = (size_t)(1-dirout)*DIRSTRIDE + (size_t)rem*768 + col;
        const float* src = dirout ? after : before;
        float xr = (src[(size_t)rem*768 + col] - mu[row]) * rstd[row] * n1w[col] + n1b[col];
        Cout[ridx] = acc[mi][ni][r] + bias[col] + bf2f(resQ[qidx]) + xr;
      }
    }
  }
}

// ---------------- qkv GEMM, per-head LN epilogue (r5 single-buffer core) --------
__global__ __launch_bounds__(256, 4) void gemm_qkv_kernel(
    const u16* __restrict__ A, const u16* __restrict__ W,
    const float* __restrict__ hw, const float* __restrict__ hb,
    u16* __restrict__ q, u16* __restrict__ k, u16* __restrict__ vt)
{
  const int K = 768, KB = 12;
  __shared__ __attribute__((aligned(16))) u16 sA[128*64];
  __shared__ __attribute__((aligned(16))) u16 sB[128*64];
  int t = threadIdx.x;
  int w = t>>6, lane = t&63, ln = lane&15, quad = lane>>4;
  int bx, by; xcd_remap(bx, by);
  int m0 = by*128, n0 = bx*128;
  int wr = (w>>1)*64, wc = (w&1)*64;
  f32x4 acc[4][4];
  #pragma unroll
  for (int mi=0;mi<4;mi++)
    #pragma unroll
    for (int ni=0;ni<4;ni++) acc[mi][ni] = (f32x4){0.f,0.f,0.f,0.f};
  for (int kb=0;kb<KB;kb++){
    __syncthreads();
    stage_tile64(A + (size_t)m0*K + kb*64, K, sA, w, lane);
    stage_tile64(W + (size_t)n0*K + kb*64, K, sB, w, lane);
    __syncthreads();
    #pragma unroll
    for (int ks=0;ks<2;ks++){
      bf16x8 aF[4], bF[4];
      #pragma unroll
      for (int mi=0;mi<4;mi++) aF[mi] = SWZ_FRAG(sA, wr+mi*16+ln, ks*4+quad);
      #pragma unroll
      for (int ni=0;ni<4;ni++) bF[ni] = SWZ_FRAG(sB, wc+ni*16+ln, ks*4+quad);
      #pragma unroll
      for (int mi=0;mi<4;mi++)
        #pragma unroll
        for (int ni=0;ni<4;ni++)
          acc[mi][ni] = __builtin_amdgcn_mfma_f32_16x16x32_bf16(aF[mi], bF[ni], acc[mi][ni], 0,0,0);
    }
  }
  // epilogue: per-row (64-wide) LayerNorm, then scatter
  int sec = (n0 + wc) >> 6;          // 0..35, wave-uniform
  int which = sec / 12, h = sec - which*12;
  float hwv[4], hbv[4];
  #pragma unroll
  for (int ni=0;ni<4;ni++){ hwv[ni] = hw[ni*16+ln]; hbv[ni] = hb[ni*16+ln]; }
  #pragma unroll
  for (int mi=0;mi<4;mi++){
    #pragma unroll
    for (int r=0;r<4;r++){
      float s = acc[mi][0][r]+acc[mi][1][r]+acc[mi][2][r]+acc[mi][3][r];
      #pragma unroll
      for (int ofs=1; ofs<16; ofs<<=1) s += __shfl_xor(s, ofs);
      float mu = s * (1.0f/64.0f);
      float vv = 0.f;
      #pragma unroll
      for (int ni=0;ni<4;ni++){ float d = acc[mi][ni][r]-mu; vv += d*d; }
      #pragma unroll
      for (int ofs=1; ofs<16; ofs<<=1) vv += __shfl_xor(vv, ofs);
      float rstd = rsqrtf(vv*(1.0f/64.0f) + 1e-5f);
      int token = m0 + wr + mi*16 + quad*4 + r;
      int dir = token >> 13, bb = (token>>10)&7, n = token & 1023;
      size_t base = (size_t)dir*DIRSTRIDE + (size_t)bb*786432 + (size_t)h*65536;
      #pragma unroll
      for (int ni=0;ni<4;ni++){
        u16 y = f2bf((acc[mi][ni][r]-mu)*rstd*hwv[ni] + hbv[ni]);
        int hd = ni*16 + ln;
        if (which == 0)      q[base + (size_t)n*64 + hd] = y;
        else if (which == 1) k[base + (size_t)n*64 + hd] = y;
        else                 vt[base + (size_t)hd*1024 + n] = y;
      }
    }
  }
}

// ---------------- flash attention v8: QBLK=128 (2 m-frags/wave) ----------------
// r8 diagnosis: LDS-throughput-bound — all 4 waves read IDENTICAL bK/bV frags
// (16 ds_read_b128/wave-iter) for only 18 MFMA. v8 gives each wave 32 q-rows:
// same 16 K/V frag reads now feed 36 MFMAs (2x work per LDS byte), barrier
// events halve (grid 3072->1536). Softmax/staging/layout otherwise identical.
__global__ __launch_bounds__(256) void flash_kernel(const u16* __restrict__ qg,
    const u16* __restrict__ kg, const u16* __restrict__ vtg, u16* __restrict__ ctx)
{
  __shared__ __attribute__((aligned(16))) u16 sK[2][64*64];
  __shared__ __attribute__((aligned(16))) u16 sV[2][64*64];
  __shared__ __attribute__((aligned(16))) u16 sP[4*32*72];
  // XCD co-location: all 8 qt-blocks of one (b,h,dout) on the same XCD.
  int lin = (int)blockIdx.x + 8*((int)blockIdx.y + 96*(int)blockIdx.z);
  int x8 = lin & 7, jj = lin >> 3;
  int qt = jj & 7;                      // 0..7, 128-row q tiles
  int g  = x8 + 8*(jj >> 3);            // 0..191, bijective
  int dout = g & 1, bh = g >> 1;
  int b = bh/12, h = bh - b*12;
  size_t qbase = (size_t)(1-dout)*DIRSTRIDE + (size_t)b*786432 + (size_t)h*65536;
  size_t kbase = (size_t)dout*DIRSTRIDE + (size_t)b*786432 + (size_t)h*65536;
  int t = threadIdx.x;
  int w = t>>6, lane = t&63, ln = lane&15, quad = lane>>4;
  // Q fragments (2 m-frags): A[m=ln][k=quad*8+j (+32)], rows w*32+mi*16+ln
  const u16* qp = qg + qbase + (size_t)(qt*128 + w*32 + ln)*64 + quad*8;
  bf16x8 aQ[2][2];
  aQ[0][0] = *(const bf16x8*)qp;
  aQ[0][1] = *(const bf16x8*)(qp + 32);
  aQ[1][0] = *(const bf16x8*)(qp + 16*64);
  aQ[1][1] = *(const bf16x8*)(qp + 16*64 + 32);
  bf16x8 vOne;
  #pragma unroll
  for (int j=0;j<8;j++) vOne[j] = (short)0x3F80;   // bf16 1.0
  f32x4 o[2][4], oL[2];
  #pragma unroll
  for (int mi=0;mi<2;mi++){
    #pragma unroll
    for (int ni=0;ni<4;ni++) o[mi][ni] = (f32x4){0.f,0.f,0.f,0.f};
    oL[mi] = (f32x4){0.f,0.f,0.f,0.f};
  }
  u16* pw = &sP[w*32*72];
  const float cs = 0.18033688011112042f;   // 0.125 * log2(e)
  // prologue: stage tile kt=0 into buffer 0
  stage_tile64x64(kg  + kbase, 64, sK[0], w, lane);               // K rows: [kt*64+n][d]
  stage_tile64x64(vtg + kbase, 1024, sV[0], w, lane);             // V^T rows: [d][kt*64+n]
  __syncthreads();
  int cur = 0;
  for (int kt=0;kt<16;kt++){
    // stage next tile into the other buffer (async; drains at end-of-iter barrier)
    if (kt < 15){
      stage_tile64x64(kg  + kbase + (size_t)(kt+1)*4096, 64, sK[cur^1], w, lane);
      stage_tile64x64(vtg + kbase + (size_t)(kt+1)*64, 1024, sV[cur^1], w, lane);
    }
    const u16* sKc = sK[cur];
    const u16* sVc = sV[cur];
    // K fragments: B[n=kv=ni*16+ln][k=d=quad*8+j(+32)] — shared by both m-frags
    bf16x8 bK[4][2];
    #pragma unroll
    for (int ni=0;ni<4;ni++){
      int rr = ni*16 + ln;
      bK[ni][0] = SWZ_FRAG(sKc, rr, quad);
      bK[ni][1] = SWZ_FRAG(sKc, rr, 4+quad);
    }
    f32x4 s[2][4];
    __builtin_amdgcn_s_setprio(1);
    #pragma unroll
    for (int mi=0;mi<2;mi++){
      #pragma unroll
      for (int ni=0;ni<4;ni++){
        s[mi][ni] = (f32x4){0.f,0.f,0.f,0.f};
        s[mi][ni] = __builtin_amdgcn_mfma_f32_16x16x32_bf16(aQ[mi][0], bK[ni][0], s[mi][ni], 0,0,0);
        s[mi][ni] = __builtin_amdgcn_mfma_f32_16x16x32_bf16(aQ[mi][1], bK[ni][1], s[mi][ni], 0,0,0);
      }
    }
    __builtin_amdgcn_s_setprio(0);
    // V fragments issued early (bK dead now); latency hides under softmax VALU
    bf16x8 bV[4][2];
    #pragma unroll
    for (int ni=0;ni<4;ni++){
      int rr = ni*16 + ln;
      bV[ni][0] = SWZ_FRAG(sVc, rr, quad);
      bV[ni][1] = SWZ_FRAG(sVc, rr, 4+quad);
    }
    // p = exp2(cs*s); bounded (per-head LN => |cs*s|<=11.7), cheap bf16 round
    #pragma unroll
    for (int mi=0;mi<2;mi++)
      #pragma unroll
      for (int ni=0;ni<4;ni++)
        #pragma unroll
        for (int r=0;r<4;r++){
          float p = exp2f(s[mi][ni][r]*cs);
          pw[(mi*16 + quad*4 + r)*72 + ni*16 + ln] = f2bf_fast(p);
        }
    // NO barrier: pw is wave-private; compiler orders ds write->read via lgkmcnt
    bf16x8 aP[2][2];
    #pragma unroll
    for (int mi=0;mi<2;mi++){
      aP[mi][0] = *(const bf16x8*)&pw[(mi*16+ln)*72 + quad*8];
      aP[mi][1] = *(const bf16x8*)&pw[(mi*16+ln)*72 + 32 + quad*8];
    }
    __builtin_amdgcn_s_setprio(1);
    #pragma unroll
    for (int mi=0;mi<2;mi++){
      #pragma unroll
      for (int ni=0;ni<4;ni++){
        o[mi][ni] = __builtin_amdgcn_mfma_f32_16x16x32_bf16(aP[mi][0], bV[ni][0], o[mi][ni], 0,0,0);
        o[mi][ni] = __builtin_amdgcn_mfma_f32_16x16x32_bf16(aP[mi][1], bV[ni][1], o[mi][ni], 0,0,0);
      }
      oL[mi] = __builtin_amdgcn_mfma_f32_16x16x32_bf16(aP[mi][0], vOne, oL[mi], 0,0,0);
      oL[mi] = __builtin_amdgcn_mfma_f32_16x16x32_bf16(aP[mi][1], vOne, oL[mi], 0,0,0);
    }
    __builtin_amdgcn_s_setprio(0);
    __syncthreads();          // single barrier/iter: next tile staged + readable
    cur ^= 1;
  }
  #pragma unroll
  for (int mi=0;mi<2;mi++){
    #pragma unroll
    for (int r=0;r<4;r++){
      float inv = 1.0f / oL[mi][r];
      int row = qt*128 + w*32 + mi*16 + quad*4 + r;
      size_t obase = ((size_t)dout*8192 + (size_t)b*1024 + row)*768 + h*64;
      #pragma unroll
      for (int ni=0;ni<4;ni++)
        ctx[obase + ni*16 + ln] = f2bf(o[mi][ni][r] * inv);
    }
  }
}

// ---------------- launcher ----------------
// Workspace layout (bytes) — total 114,950,144 (~110 MiB); h1 f32 lives in d_out.
//   [0,          25165824)  xn bf16    (ln -> qkv gemm), then ctx bf16 (flash -> proj)
//   [25165824,   50331648)  q bf16     (qkv -> proj)
//       [0, 50331648)       g bf16 chunk scratch for MLP (after proj)
//   [50331648,   75497472)  k bf16     (qkv -> flash), then h1n bf16 (ln2 -> fc1)
//   [75497472,  100663296)  vt bf16    (qkv -> flash)
//   [100663296, 114819072)  bf16 weights (qkv,proj,fc1,fc2)
//   [114819072, 114950144)  norm1 mu/rstd f32[16384] each
extern "C" void kernel_launch(void* const* d_in, const int* in_sizes, int n_in,
                              void* d_out, int out_size, void* d_ws, size_t ws_size,
                              hipStream_t stream)
{
  const float* before = (const float*)d_in[0];
  const float* after  = (const float*)d_in[1];
  const float* n1w  = (const float*)d_in[2];
  const float* n1b  = (const float*)d_in[3];
  const float* qkvw = (const float*)d_in[4];
  const float* hlnw = (const float*)d_in[5];
  const float* hlnb = (const float*)d_in[6];
  const float* projw= (const float*)d_in[7];
  const float* projb= (const float*)d_in[8];
  const float* n2w  = (const float*)d_in[9];
  const float* n2b  = (const float*)d_in[10];
  const float* fc1w = (const float*)d_in[11];
  const float* fc1b = (const float*)d_in[12];
  const float* fc2w = (const float*)d_in[13];
  const float* fc2b = (const float*)d_in[14];

  const size_t REQUIRED = 114950144;
  if (ws_size < REQUIRED){
    // Diagnostic fallback: never touch d_ws; clean test failure instead of fault.
    zero_kernel<<<(out_size + 255)/256, 256, 0, stream>>>((float*)d_out, out_size);
    return;
  }

  char* ws = (char*)d_ws;
  u16* xn    = (u16*)(ws + 0);
  u16* ctxb  = (u16*)(ws + 0);            // reuse xn slot (xn dead after qkv gemm)
  u16* gbuf  = (u16*)(ws + 0);            // MLP chunk scratch (ctx+q dead by then)
  u16* qb    = (u16*)(ws + 25165824);
  u16* kb    = (u16*)(ws + 50331648);
  u16* h1n   = (u16*)(ws + 50331648);     // reuse k slot (k dead after flash)
  u16* vtb   = (u16*)(ws + 75497472);
  u16* wqkv  = (u16*)(ws + 100663296);
  u16* wproj = (u16*)(ws + 104202240);
  u16* wfc1  = (u16*)(ws + 105381888);
  u16* wfc2  = (u16*)(ws + 110100480);
  float* mu1  = (float*)(ws + 114819072);
  float* rs1  = (float*)(ws + 114884608);
  float* h1   = (float*)d_out;            // h1 f32 scratch lives in d_out
  float* outp = (float*)d_out;

  cvt_kernel<<<6912, 256, 0, stream>>>(qkvw, wqkv, 1769472);
  cvt_kernel<<<2304, 256, 0, stream>>>(projw, wproj, 589824);
  cvt_kernel<<<9216, 256, 0, stream>>>(fc1w, wfc1, 2359296);
  cvt_kernel<<<9216, 256, 0, stream>>>(fc2w, wfc2, 2359296);

  // 1) LN(before), LN(after) -> xn bf16 (+ stats for residual recompute)
  ln_kernel<<<16384, 256, 0, stream>>>(before, after, n1w, n1b, xn, mu1, rs1);
  // 2) qkv = xn @ qkv_w^T, fused per-head LN, scatter to q,k,v^T (xn dies here)
  gemm_qkv_kernel<<<dim3(18,128), 256, 0, stream>>>(xn, wqkv, hlnw, hlnb, qb, kb, vtb);
  // 3) cross attention; ctx overwrites xn slot (dirout0: q from after, k/v from before)
  flash_kernel<<<dim3(8,96,2), 256, 0, stream>>>(qb, kb, vtb, ctxb);
  // 4) h1 = ctx @ proj_w^T + proj_b + q_scrambled + LN(x) recomputed  (f32, into d_out)
  gemm_proj_kernel<<<dim3(6,128), 256, 0, stream>>>(ctxb, wproj, h1,
      projb, qb, before, after, n1w, n1b, mu1, rs1);
  // 5) h1n = LN(h1) bf16 (k slot)
  ln_kernel<<<16384, 256, 0, stream>>>(h1, h1 + (size_t)8192*768, n2w, n2b, h1n,
      nullptr, nullptr);
  // 6/7) MLP in two row-chunks of 8192 (g scratch = 50.3 MB in ctx+q slots)
  for (int c = 0; c < 2; c++){
    size_t off = (size_t)c * 8192 * 768;       // elements into (16384,768)
    gemm_kernel<2><<<dim3(24,64), 256, 0, stream>>>(h1n + off, wfc1, gbuf,
        fc1b, nullptr, 8192, 3072, 768);
    gemm_fc2_kernel<<<dim3(12,64), 256, 0, stream>>>(gbuf, wfc2, outp + off,
        fc2b, h1 + off);
  }
}